// Round 3
// baseline (6376.761 us; speedup 1.0000x reference)
//
#include <hip/hip_runtime.h>
#include <hip/hip_bf16.h>
#include <math.h>

// Problem constants
#define NB    2
#define SEQ   2048
#define DMODEL 1024
#define NH    16
#define HDIM  64
#define NE    8
#define DFF   4096
#define TTOK  4096   // NB*SEQ

typedef __attribute__((ext_vector_type(8))) short short8;
typedef __attribute__((ext_vector_type(4))) float f32x4;
typedef __attribute__((ext_vector_type(4))) unsigned int uint4v;

static __device__ __forceinline__ float bf2f(unsigned short u) {
  union { unsigned int i; float f; } c; c.i = ((unsigned int)u) << 16; return c.f;
}
static __device__ __forceinline__ unsigned short f2bf(float f) {
  unsigned int x = __float_as_uint(f);
  unsigned int r = (x + 0x7FFFu + ((x >> 16) & 1u)) >> 16;
  return (unsigned short)r;
}

// ---------------------------------------------------------------------------
// LayerNorm: one block (256 thr) per token. fp32 in. BF16OUT selects output.
// ---------------------------------------------------------------------------
template<bool BF16OUT>
__global__ __launch_bounds__(256) void ln_kernel(
    const float* __restrict__ x,
    const float* __restrict__ gam,
    const float* __restrict__ bet,
    float* __restrict__ outf,
    unsigned short* __restrict__ outb)
{
  int t = blockIdx.x, tid = threadIdx.x;
  f32x4 v = ((const f32x4*)(x + (size_t)t * DMODEL))[tid];
  float s  = v[0] + v[1] + v[2] + v[3];
  float sq = v[0]*v[0] + v[1]*v[1] + v[2]*v[2] + v[3]*v[3];
  #pragma unroll
  for (int off = 1; off < 64; off <<= 1) {
    s  += __shfl_xor(s, off);
    sq += __shfl_xor(sq, off);
  }
  __shared__ float red[8];
  int w = tid >> 6, l = tid & 63;
  if (l == 0) { red[w] = s; red[4 + w] = sq; }
  __syncthreads();
  s  = red[0] + red[1] + red[2] + red[3];
  sq = red[4] + red[5] + red[6] + red[7];
  float mu  = s * (1.0f / DMODEL);
  float var = sq * (1.0f / DMODEL) - mu * mu;
  float rs  = rsqrtf(var + 1e-5f);
  f32x4 g = ((const f32x4*)gam)[tid];
  f32x4 b = ((const f32x4*)bet)[tid];
  float r0 = (v[0] - mu) * rs * g[0] + b[0];
  float r1 = (v[1] - mu) * rs * g[1] + b[1];
  float r2 = (v[2] - mu) * rs * g[2] + b[2];
  float r3 = (v[3] - mu) * rs * g[3] + b[3];
  if constexpr (BF16OUT) {
    ushort4 o; o.x = f2bf(r0); o.y = f2bf(r1); o.z = f2bf(r2); o.w = f2bf(r3);
    ((ushort4*)(outb + (size_t)t * DMODEL))[tid] = o;
  } else {
    f32x4 o = {r0, r1, r2, r3};
    ((f32x4*)(outf + (size_t)t * DMODEL))[tid] = o;
  }
}

// ---------------------------------------------------------------------------
// fp32 vector SGEMM, 64x64 tile, BK=16, 256 threads, 4x4 per thread.
// EPI 0: C = A@B + bias.  EPI 1: C = A@B + bias + resid.
// Used only on the (precision-critical, small-FLOP) attention path.
// ---------------------------------------------------------------------------
template<int EPI>
__global__ __launch_bounds__(256) void sgemm64(
    const float* __restrict__ A, const float* __restrict__ B,
    const float* __restrict__ bias, const float* __restrict__ resid,
    float* __restrict__ C, int M, int N, int K)
{
  __shared__ float As[16][68];
  __shared__ float Bs[16][68];
  int tid = threadIdx.x;
  int tx = tid & 15, ty = tid >> 4;
  int m0 = blockIdx.y * 64, n0 = blockIdx.x * 64;
  float c[4][4] = {};
  for (int k0 = 0; k0 < K; k0 += 16) {
    __syncthreads();
    #pragma unroll
    for (int i = 0; i < 4; ++i) {
      int e = tid + i * 256;           // A: 64 rows x 16 k
      int m = e >> 4, k = e & 15;
      As[k][m] = A[(size_t)(m0 + m) * K + k0 + k];
    }
    #pragma unroll
    for (int i = 0; i < 4; ++i) {
      int e = tid + i * 256;           // B: 16 k x 64 n
      int k = e >> 6, n = e & 63;
      Bs[k][n] = B[(size_t)(k0 + k) * N + n0 + n];
    }
    __syncthreads();
    #pragma unroll
    for (int k = 0; k < 16; ++k) {
      f32x4 a = *(const f32x4*)(&As[k][ty << 2]);
      f32x4 b = *(const f32x4*)(&Bs[k][tx << 2]);
      #pragma unroll
      for (int i = 0; i < 4; ++i)
        #pragma unroll
        for (int j = 0; j < 4; ++j)
          c[i][j] = fmaf(a[i], b[j], c[i][j]);
    }
  }
  #pragma unroll
  for (int i = 0; i < 4; ++i) {
    int row = m0 + (ty << 2) + i;
    #pragma unroll
    for (int j = 0; j < 4; ++j) {
      int col = n0 + (tx << 2) + j;
      float v = c[i][j] + bias[col];
      if constexpr (EPI == 1) v += resid[(size_t)row * N + col];
      C[(size_t)row * N + col] = v;
    }
  }
}

// ---------------------------------------------------------------------------
// bf16-A x fp32-B MFMA GEMM, 128x128 tile, BK=32, 4 waves (2x2), 16x16x32.
// A[M][K] bf16 row-major; B[K][N] fp32 row-major (converted at stage time).
// EPI: 1=gelu->bf16, 3=gate-weighted atomicAdd into fp32.  (MoE only.)
// ---------------------------------------------------------------------------
template<int EPI>
__global__ __launch_bounds__(256) void gemm128(
    const unsigned short* __restrict__ A,
    const float* __restrict__ Bm,
    const float* __restrict__ bias,
    unsigned short* __restrict__ Cb,
    float* __restrict__ Cf,
    const float* __restrict__ gates,
    int M, int N, int K, int expert)
{
  __shared__ unsigned short Al[128][40];
  __shared__ unsigned short Bl[128][40];
  int tid = threadIdx.x;
  int l = tid & 63, w = tid >> 6;
  int wr = w >> 1, wc = w & 1;
  int m0 = blockIdx.y * 128, n0 = blockIdx.x * 128;

  const f32x4 z = {0.f, 0.f, 0.f, 0.f};
  f32x4 acc[4][4];
  #pragma unroll
  for (int i = 0; i < 4; ++i)
    #pragma unroll
    for (int j = 0; j < 4; ++j) acc[i][j] = z;

  for (int k0 = 0; k0 < K; k0 += 32) {
    __syncthreads();
    // stage A (bf16): 128 rows x 32 cols
    for (int c = tid; c < 512; c += 256) {
      int row = c >> 2, kc = (c & 3) << 3;
      uint4v v = *(const uint4v*)(A + (size_t)(m0 + row) * K + k0 + kc);
      *(uint4v*)(&Al[row][kc]) = v;
    }
    // stage B (fp32 -> bf16) transposed: 32 k-rows x 32 n-chunks of 4
    for (int c = tid; c < 1024; c += 256) {
      int k = c >> 5, nc = (c & 31) << 2;
      f32x4 v = *(const f32x4*)(Bm + (size_t)(k0 + k) * N + n0 + nc);
      Bl[nc + 0][k] = f2bf(v[0]);
      Bl[nc + 1][k] = f2bf(v[1]);
      Bl[nc + 2][k] = f2bf(v[2]);
      Bl[nc + 3][k] = f2bf(v[3]);
    }
    __syncthreads();

    short8 af[4], bfr[4];
    #pragma unroll
    for (int m = 0; m < 4; ++m)
      af[m] = *(const short8*)(&Al[wr * 64 + m * 16 + (l & 15)][(l >> 4) << 3]);
    #pragma unroll
    for (int n = 0; n < 4; ++n)
      bfr[n] = *(const short8*)(&Bl[wc * 64 + n * 16 + (l & 15)][(l >> 4) << 3]);
    #pragma unroll
    for (int m = 0; m < 4; ++m)
      #pragma unroll
      for (int n = 0; n < 4; ++n)
        acc[m][n] = __builtin_amdgcn_mfma_f32_16x16x32_bf16(af[m], bfr[n], acc[m][n], 0, 0, 0);
  }

  int rbase = m0 + wr * 64 + ((l >> 4) << 2);
  int cbase = n0 + wc * 64 + (l & 15);
  #pragma unroll
  for (int n = 0; n < 4; ++n) {
    int col = cbase + n * 16;
    float bv = bias[col];
    #pragma unroll
    for (int m = 0; m < 4; ++m) {
      #pragma unroll
      for (int r = 0; r < 4; ++r) {
        int row = rbase + m * 16 + r;
        float v = acc[m][n][r] + bv;
        if constexpr (EPI == 1) {
          v = 0.5f * v * (1.0f + erff(v * 0.70710678118654752f));
          Cb[(size_t)row * N + col] = f2bf(v);
        } else {
          float g = gates[row * NE + expert];
          if (g != 0.0f) atomicAdd(&Cf[(size_t)row * N + col], g * v);
        }
      }
    }
  }
}

// ---------------------------------------------------------------------------
// Causal flash attention, full fp32. Grid (8, B*H); block 256.
// Thread owns one q-row. K/V tiles of 64 rows staged to LDS.
// qkv is fp32 [T][3][H][HD].
// ---------------------------------------------------------------------------
__global__ __launch_bounds__(256) void attn_kernel(
    const float* __restrict__ qkv,
    float* __restrict__ ctx)
{
  __shared__ float Klf[64][64];
  __shared__ float Vlf[64][64];
  int bh = blockIdx.y;
  int b = bh >> 4, h = bh & 15;
  int tid = threadIdx.x;
  int q = blockIdx.x * 256 + tid;
  const int bS = b * SEQ;

  float qreg[64];
  {
    const f32x4* qp = (const f32x4*)(qkv + ((size_t)(bS + q)) * 3072 + h * HDIM);
    #pragma unroll
    for (int c = 0; c < 16; ++c) {
      f32x4 u = qp[c];
      qreg[c * 4 + 0] = u[0]; qreg[c * 4 + 1] = u[1];
      qreg[c * 4 + 2] = u[2]; qreg[c * 4 + 3] = u[3];
    }
  }
  float o[64];
  #pragma unroll
  for (int e = 0; e < 64; ++e) o[e] = 0.0f;
  float mrun = -1e30f, lrun = 0.0f;

  int nt = blockIdx.x * 4 + 4;
  for (int kt = 0; kt < nt; ++kt) {
    __syncthreads();
    for (int c = tid; c < 1024; c += 256) {
      int r = c >> 4, cc = (c & 15) << 2;
      size_t gk = ((size_t)(bS + kt * 64 + r)) * 3072 + DMODEL + h * HDIM + cc;
      *(f32x4*)(&Klf[r][cc]) = *(const f32x4*)(qkv + gk);
      *(f32x4*)(&Vlf[r][cc]) = *(const f32x4*)(qkv + gk + DMODEL);
    }
    __syncthreads();
    if (q >= kt * 64) {
      int jmax = q - kt * 64; if (jmax > 63) jmax = 63;
      #pragma unroll
      for (int ch = 0; ch < 2; ++ch) {
        int jbase = ch * 32;
        if (jbase > jmax) break;
        float s[32];
        float tm = -1e30f;
        #pragma unroll
        for (int j = 0; j < 32; ++j) {
          int jj = jbase + j;
          float d = 0.0f;
          const f32x4* krow = (const f32x4*)(&Klf[jj][0]);
          #pragma unroll
          for (int ec = 0; ec < 16; ++ec) {
            f32x4 kvv = krow[ec];
            d += qreg[ec * 4 + 0] * kvv[0];
            d += qreg[ec * 4 + 1] * kvv[1];
            d += qreg[ec * 4 + 2] * kvv[2];
            d += qreg[ec * 4 + 3] * kvv[3];
          }
          s[j] = (jj <= jmax) ? d * 0.125f : -1e30f;
          tm = fmaxf(tm, s[j]);
        }
        float nm = fmaxf(mrun, tm);
        float scale = __expf(mrun - nm);
        lrun *= scale;
        #pragma unroll
        for (int e = 0; e < 64; ++e) o[e] *= scale;
        #pragma unroll
        for (int j = 0; j < 32; ++j) {
          float p = __expf(s[j] - nm);
          lrun += p;
          const f32x4* vrow = (const f32x4*)(&Vlf[jbase + j][0]);
          #pragma unroll
          for (int ec = 0; ec < 16; ++ec) {
            f32x4 vvv = vrow[ec];
            o[ec * 4 + 0] += p * vvv[0];
            o[ec * 4 + 1] += p * vvv[1];
            o[ec * 4 + 2] += p * vvv[2];
            o[ec * 4 + 3] += p * vvv[3];
          }
        }
        mrun = nm;
      }
    }
  }
  float inv = 1.0f / lrun;
  float* orow = ctx + ((size_t)(bS + q)) * DMODEL + h * HDIM;
  #pragma unroll
  for (int c = 0; c < 16; ++c) {
    f32x4 pk;
    pk[0] = o[c * 4 + 0] * inv;
    pk[1] = o[c * 4 + 1] * inv;
    pk[2] = o[c * 4 + 2] * inv;
    pk[3] = o[c * 4 + 3] * inv;
    ((f32x4*)orow)[c] = pk;
  }
}

// ---------------------------------------------------------------------------
// Router (full fp32): one wave per token. Recomputes LN2 from x1 (fp32),
// then logits, softmax top-2 normalized -> dense gates [T][8].
// Ties break to lower expert index (matches jax.lax.top_k).
// ---------------------------------------------------------------------------
__global__ __launch_bounds__(256) void router_kernel(
    const float* __restrict__ x1,
    const float* __restrict__ gam,
    const float* __restrict__ bet,
    const float* __restrict__ wrt,
    float* __restrict__ gates)
{
  int w = threadIdx.x >> 6, l = threadIdx.x & 63;
  int t = blockIdx.x * 4 + w;
  const f32x4* row = (const f32x4*)(x1 + (size_t)t * DMODEL);
  f32x4 v[4];
  float s = 0.f, sq = 0.f;
  #pragma unroll
  for (int i = 0; i < 4; ++i) {
    v[i] = row[l + i * 64];
    #pragma unroll
    for (int j = 0; j < 4; ++j) { s += v[i][j]; sq += v[i][j] * v[i][j]; }
  }
  #pragma unroll
  for (int off = 1; off < 64; off <<= 1) {
    s  += __shfl_xor(s, off);
    sq += __shfl_xor(sq, off);
  }
  float mu  = s * (1.0f / DMODEL);
  float var = sq * (1.0f / DMODEL) - mu * mu;
  float rs  = rsqrtf(var + 1e-5f);

  float acc[NE] = {0.f, 0.f, 0.f, 0.f, 0.f, 0.f, 0.f, 0.f};
  #pragma unroll
  for (int i = 0; i < 4; ++i) {
    int base = (l + i * 64) * 4;
    #pragma unroll
    for (int j = 0; j < 4; ++j) {
      int idx = base + j;
      float xn = (v[i][j] - mu) * rs * gam[idx] + bet[idx];
      const f32x4* wr0 = (const f32x4*)(wrt + idx * NE);
      f32x4 w0 = wr0[0], w1v = wr0[1];
      acc[0] += xn * w0[0]; acc[1] += xn * w0[1];
      acc[2] += xn * w0[2]; acc[3] += xn * w0[3];
      acc[4] += xn * w1v[0]; acc[5] += xn * w1v[1];
      acc[6] += xn * w1v[2]; acc[7] += xn * w1v[3];
    }
  }
  #pragma unroll
  for (int e = 0; e < NE; ++e) {
    #pragma unroll
    for (int off = 1; off < 64; off <<= 1) acc[e] += __shfl_xor(acc[e], off);
  }
  if (l == 0) {
    int e0 = 0; float m0v = acc[0];
    #pragma unroll
    for (int e = 1; e < NE; ++e) if (acc[e] > m0v) { m0v = acc[e]; e0 = e; }
    int e1 = -1; float m1v = -1e30f;
    #pragma unroll
    for (int e = 0; e < NE; ++e) if (e != e0 && acc[e] > m1v) { m1v = acc[e]; e1 = e; }
    float r = __expf(m1v - m0v);      // p1/p0
    float g0 = 1.0f / (1.0f + r);
    float g1 = r * g0;
    #pragma unroll
    for (int e = 0; e < NE; ++e)
      gates[t * NE + e] = (e == e0) ? g0 : ((e == e1) ? g1 : 0.0f);
  }
}

// ---------------------------------------------------------------------------
// out = x1 + ffn   (all fp32)
// ---------------------------------------------------------------------------
__global__ __launch_bounds__(256) void final_add(
    const float* __restrict__ x1,
    const float* __restrict__ ffn,
    float* __restrict__ out)
{
  int i = blockIdx.x * 256 + threadIdx.x;
  f32x4 xr = ((const f32x4*)x1)[i];
  f32x4 fr = ((const f32x4*)ffn)[i];
  f32x4 o;
  o[0] = xr[0] + fr[0];
  o[1] = xr[1] + fr[1];
  o[2] = xr[2] + fr[2];
  o[3] = xr[3] + fr[3];
  ((f32x4*)out)[i] = o;
}

// ---------------------------------------------------------------------------
extern "C" void kernel_launch(void* const* d_in, const int* in_sizes, int n_in,
                              void* d_out, int out_size, void* d_ws, size_t ws_size,
                              hipStream_t stream) {
  (void)in_sizes; (void)n_in; (void)out_size; (void)ws_size;
  const float* x     = (const float*)d_in[0];
  const float* ln1_g = (const float*)d_in[1];
  const float* ln1_b = (const float*)d_in[2];
  const float* ln2_g = (const float*)d_in[3];
  const float* ln2_b = (const float*)d_in[4];
  const float* wqkv  = (const float*)d_in[5];
  const float* bqkv  = (const float*)d_in[6];
  const float* wo    = (const float*)d_in[7];
  const float* bo    = (const float*)d_in[8];
  const float* wrt   = (const float*)d_in[9];
  const float* w1    = (const float*)d_in[10];
  const float* b1    = (const float*)d_in[11];
  const float* w2    = (const float*)d_in[12];
  const float* b2    = (const float*)d_in[13];
  float* out = (float*)d_out;

  char* ws = (char*)d_ws;
  size_t off = 0;
  auto alloc = [&](size_t bytes) -> void* {
    void* p = ws + off;
    off += (bytes + 255) & ~(size_t)255;
    return p;
  };
  float*          h    = (float*)alloc((size_t)TTOK * DMODEL * 4);
  float*          qkv  = (float*)alloc((size_t)TTOK * 3 * DMODEL * 4);
  float*          ctx  = (float*)alloc((size_t)TTOK * DMODEL * 4);
  float*          x1   = (float*)alloc((size_t)TTOK * DMODEL * 4);
  unsigned short* h2   = (unsigned short*)alloc((size_t)TTOK * DMODEL * 2);
  float*          gts  = (float*)alloc((size_t)TTOK * NE * 4);
  unsigned short* Hbuf = (unsigned short*)alloc((size_t)TTOK * DFF * 2);
  float*          ffn  = (float*)alloc((size_t)TTOK * DMODEL * 4);

  // 1) h = LN1(x)                       (fp32)
  ln_kernel<false><<<TTOK, 256, 0, stream>>>(x, ln1_g, ln1_b, h, nullptr);
  // 2) qkv = h @ wqkv + bqkv            (fp32 SGEMM — precision-critical path)
  sgemm64<0><<<dim3(3 * DMODEL / 64, TTOK / 64), 256, 0, stream>>>(
      h, wqkv, bqkv, nullptr, qkv, TTOK, 3 * DMODEL, DMODEL);
  // 3) ctx = causal attention           (fp32)
  attn_kernel<<<dim3(SEQ / 256, NB * NH), 256, 0, stream>>>(qkv, ctx);
  // 4) x1 = x + ctx @ wo + bo           (fp32 SGEMM)
  sgemm64<1><<<dim3(DMODEL / 64, TTOK / 64), 256, 0, stream>>>(
      ctx, wo, bo, x, x1, TTOK, DMODEL, DMODEL);
  // 5) h2 = LN2(x1)                     (bf16, feeds MoE MFMA GEMMs)
  ln_kernel<true><<<TTOK, 256, 0, stream>>>(x1, ln2_g, ln2_b, nullptr, h2);
  // 6) router gates (fp32 path, own LN)
  router_kernel<<<TTOK / 4, 256, 0, stream>>>(x1, ln2_g, ln2_b, wrt, gts);
  // 7) MoE: dense per-expert bf16 MFMA, gate-weighted accumulate into fp32
  hipMemsetAsync(ffn, 0, (size_t)TTOK * DMODEL * 4, stream);
  for (int e = 0; e < NE; ++e) {
    gemm128<1><<<dim3(DFF / 128, TTOK / 128), 256, 0, stream>>>(
        h2, w1 + (size_t)e * DMODEL * DFF, b1 + (size_t)e * DFF,
        Hbuf, nullptr, nullptr, TTOK, DFF, DMODEL, 0);
    gemm128<3><<<dim3(DMODEL / 128, TTOK / 128), 256, 0, stream>>>(
        Hbuf, w2 + (size_t)e * DFF * DMODEL, b2 + (size_t)e * DMODEL,
        nullptr, ffn, gts, TTOK, DMODEL, DFF, e);
  }
  // 8) out = x1 + ffn  (fp32)
  final_add<<<(TTOK * DMODEL / 4) / 256, 256, 0, stream>>>(x1, ffn, out);
}

// Round 4
// 2349.240 us; speedup vs baseline: 2.7144x; 2.7144x over previous
//
#include <hip/hip_runtime.h>
#include <hip/hip_bf16.h>
#include <math.h>

// Problem constants
#define NB    2
#define SEQ   2048
#define DMODEL 1024
#define NH    16
#define HDIM  64
#define NE    8
#define DFF   4096
#define TTOK  4096   // NB*SEQ

#define MT_MAX   72     // worst-case m-tiles over all experts (128-padded)
#define SLOT_MAX 9216   // worst-case padded slot count (2*TTOK + 8*127, rounded)

// ctrl block layout (ints)
#define C_CNT  0    // [8]  per-expert token counts
#define C_FILL 8    // [8]  gather fill cursors
#define C_BASE 16   // [8]  per-expert slot base
#define C_NMT  24   // [1]  number of m-tiles
#define C_MTE  32   // [72] m-tile -> expert
#define C_MTS  104  // [72] m-tile -> slot base

typedef __attribute__((ext_vector_type(8))) short short8;
typedef __attribute__((ext_vector_type(4))) float f32x4;
typedef __attribute__((ext_vector_type(4))) unsigned int uint4v;

static __device__ __forceinline__ unsigned short f2bf(float f) {
  unsigned int x = __float_as_uint(f);
  unsigned int r = (x + 0x7FFFu + ((x >> 16) & 1u)) >> 16;
  return (unsigned short)r;
}

// ---------------------------------------------------------------------------
// LayerNorm: one block (256 thr) per token. fp32 in. BF16OUT selects output.
// ---------------------------------------------------------------------------
template<bool BF16OUT>
__global__ __launch_bounds__(256) void ln_kernel(
    const float* __restrict__ x,
    const float* __restrict__ gam,
    const float* __restrict__ bet,
    float* __restrict__ outf,
    unsigned short* __restrict__ outb)
{
  int t = blockIdx.x, tid = threadIdx.x;
  f32x4 v = ((const f32x4*)(x + (size_t)t * DMODEL))[tid];
  float s  = v[0] + v[1] + v[2] + v[3];
  float sq = v[0]*v[0] + v[1]*v[1] + v[2]*v[2] + v[3]*v[3];
  #pragma unroll
  for (int off = 1; off < 64; off <<= 1) {
    s  += __shfl_xor(s, off);
    sq += __shfl_xor(sq, off);
  }
  __shared__ float red[8];
  int w = tid >> 6, l = tid & 63;
  if (l == 0) { red[w] = s; red[4 + w] = sq; }
  __syncthreads();
  s  = red[0] + red[1] + red[2] + red[3];
  sq = red[4] + red[5] + red[6] + red[7];
  float mu  = s * (1.0f / DMODEL);
  float var = sq * (1.0f / DMODEL) - mu * mu;
  float rs  = rsqrtf(var + 1e-5f);
  f32x4 g = ((const f32x4*)gam)[tid];
  f32x4 b = ((const f32x4*)bet)[tid];
  float r0 = (v[0] - mu) * rs * g[0] + b[0];
  float r1 = (v[1] - mu) * rs * g[1] + b[1];
  float r2 = (v[2] - mu) * rs * g[2] + b[2];
  float r3 = (v[3] - mu) * rs * g[3] + b[3];
  if constexpr (BF16OUT) {
    ushort4 o; o.x = f2bf(r0); o.y = f2bf(r1); o.z = f2bf(r2); o.w = f2bf(r3);
    ((ushort4*)(outb + (size_t)t * DMODEL))[tid] = o;
  } else {
    f32x4 o = {r0, r1, r2, r3};
    ((f32x4*)(outf + (size_t)t * DMODEL))[tid] = o;
  }
}

// ---------------------------------------------------------------------------
// fp32 vector SGEMM, 64x64 tile, BK=16, 256 threads, 4x4 per thread.
// EPI 0: C = A@B + bias.  EPI 1: C = A@B + bias + resid.
// Used only on the (precision-critical, small-FLOP) attention path.
// ---------------------------------------------------------------------------
template<int EPI>
__global__ __launch_bounds__(256) void sgemm64(
    const float* __restrict__ A, const float* __restrict__ B,
    const float* __restrict__ bias, const float* __restrict__ resid,
    float* __restrict__ C, int M, int N, int K)
{
  __shared__ float As[16][68];
  __shared__ float Bs[16][68];
  int tid = threadIdx.x;
  int tx = tid & 15, ty = tid >> 4;
  int m0 = blockIdx.y * 64, n0 = blockIdx.x * 64;
  float c[4][4] = {};
  for (int k0 = 0; k0 < K; k0 += 16) {
    __syncthreads();
    #pragma unroll
    for (int i = 0; i < 4; ++i) {
      int e = tid + i * 256;           // A: 64 rows x 16 k
      int m = e >> 4, k = e & 15;
      As[k][m] = A[(size_t)(m0 + m) * K + k0 + k];
    }
    #pragma unroll
    for (int i = 0; i < 4; ++i) {
      int e = tid + i * 256;           // B: 16 k x 64 n
      int k = e >> 6, n = e & 63;
      Bs[k][n] = B[(size_t)(k0 + k) * N + n0 + n];
    }
    __syncthreads();
    #pragma unroll
    for (int k = 0; k < 16; ++k) {
      f32x4 a = *(const f32x4*)(&As[k][ty << 2]);
      f32x4 b = *(const f32x4*)(&Bs[k][tx << 2]);
      #pragma unroll
      for (int i = 0; i < 4; ++i)
        #pragma unroll
        for (int j = 0; j < 4; ++j)
          c[i][j] = fmaf(a[i], b[j], c[i][j]);
    }
  }
  #pragma unroll
  for (int i = 0; i < 4; ++i) {
    int row = m0 + (ty << 2) + i;
    #pragma unroll
    for (int j = 0; j < 4; ++j) {
      int col = n0 + (tx << 2) + j;
      float v = c[i][j] + bias[col];
      if constexpr (EPI == 1) v += resid[(size_t)row * N + col];
      C[(size_t)row * N + col] = v;
    }
  }
}

// ---------------------------------------------------------------------------
// Causal flash attention, fp32, 4 threads per q-row.
// Grid (SEQ/64, B*H); block 256 = 64 q-rows x 4 dim-slices of 16.
// ---------------------------------------------------------------------------
__global__ __launch_bounds__(256) void attn4_kernel(
    const float* __restrict__ qkv,
    float* __restrict__ ctx)
{
  __shared__ float Kl[64][64];
  __shared__ float Vl[64][64];
  int bh = blockIdx.y;
  int b = bh >> 4, h = bh & 15;
  int tid = threadIdx.x;
  int ql = tid >> 2, part = tid & 3;
  int q = blockIdx.x * 64 + ql;
  const int bS = b * SEQ;
  const int d0 = part * 16;

  f32x4 qreg[4];
  {
    const f32x4* qp = (const f32x4*)(qkv + ((size_t)(bS + q)) * 3072 + h * HDIM + d0);
    qreg[0] = qp[0]; qreg[1] = qp[1]; qreg[2] = qp[2]; qreg[3] = qp[3];
  }
  f32x4 o[4];
  o[0] = o[1] = o[2] = o[3] = (f32x4){0.f, 0.f, 0.f, 0.f};
  float mrun = -1e30f, lrun = 0.0f;

  int nt = blockIdx.x + 1;
  for (int kt = 0; kt < nt; ++kt) {
    __syncthreads();
    {
      int r = tid >> 2, cc = (tid & 3) * 16;
      size_t gk = ((size_t)(bS + kt * 64 + r)) * 3072 + DMODEL + h * HDIM + cc;
      const f32x4* kp = (const f32x4*)(qkv + gk);
      const f32x4* vp = (const f32x4*)(qkv + gk + DMODEL);
      f32x4* kd = (f32x4*)(&Kl[r][cc]);
      f32x4* vd = (f32x4*)(&Vl[r][cc]);
      kd[0] = kp[0]; kd[1] = kp[1]; kd[2] = kp[2]; kd[3] = kp[3];
      vd[0] = vp[0]; vd[1] = vp[1]; vd[2] = vp[2]; vd[3] = vp[3];
    }
    __syncthreads();
    int jmax = q - kt * 64; if (jmax > 63) jmax = 63;
    for (int jb = 0; jb <= jmax; jb += 16) {
      float sv[16];
      float cm = -1e30f;
      #pragma unroll
      for (int j = 0; j < 16; ++j) {
        int jj = jb + j;
        const f32x4* kr = (const f32x4*)(&Kl[jj][d0]);
        f32x4 a0 = kr[0], a1 = kr[1], a2 = kr[2], a3 = kr[3];
        float d =
          qreg[0][0]*a0[0] + qreg[0][1]*a0[1] + qreg[0][2]*a0[2] + qreg[0][3]*a0[3] +
          qreg[1][0]*a1[0] + qreg[1][1]*a1[1] + qreg[1][2]*a1[2] + qreg[1][3]*a1[3] +
          qreg[2][0]*a2[0] + qreg[2][1]*a2[1] + qreg[2][2]*a2[2] + qreg[2][3]*a2[3] +
          qreg[3][0]*a3[0] + qreg[3][1]*a3[1] + qreg[3][2]*a3[2] + qreg[3][3]*a3[3];
        d += __shfl_xor(d, 1);
        d += __shfl_xor(d, 2);
        sv[j] = (jj <= jmax) ? d * 0.125f : -1e30f;
        cm = fmaxf(cm, sv[j]);
      }
      float nm = fmaxf(mrun, cm);
      float sc = __expf(mrun - nm);
      lrun *= sc;
      o[0] = o[0] * sc; o[1] = o[1] * sc; o[2] = o[2] * sc; o[3] = o[3] * sc;
      #pragma unroll
      for (int j = 0; j < 16; ++j) {
        float p = __expf(sv[j] - nm);
        lrun += p;
        const f32x4* vr = (const f32x4*)(&Vl[jb + j][d0]);
        o[0] += p * vr[0]; o[1] += p * vr[1]; o[2] += p * vr[2]; o[3] += p * vr[3];
      }
      mrun = nm;
    }
  }
  float inv = 1.0f / lrun;
  float* orow = ctx + ((size_t)(bS + q)) * DMODEL + h * HDIM + d0;
  ((f32x4*)orow)[0] = o[0] * inv;
  ((f32x4*)orow)[1] = o[1] * inv;
  ((f32x4*)orow)[2] = o[2] * inv;
  ((f32x4*)orow)[3] = o[3] * inv;
}

// ---------------------------------------------------------------------------
// Router (fp32): one wave per token. Recomputes LN2 from x1, logits, top-2.
// Emits per-token expert pair + normalized gates; counts per expert.
// ---------------------------------------------------------------------------
__global__ __launch_bounds__(256) void router_kernel(
    const float* __restrict__ x1,
    const float* __restrict__ gam,
    const float* __restrict__ bet,
    const float* __restrict__ wrt,
    int* __restrict__ ctrl,
    int2* __restrict__ t_e,
    float2* __restrict__ t_g)
{
  int w = threadIdx.x >> 6, l = threadIdx.x & 63;
  int t = blockIdx.x * 4 + w;
  const f32x4* row = (const f32x4*)(x1 + (size_t)t * DMODEL);
  f32x4 v[4];
  float s = 0.f, sq = 0.f;
  #pragma unroll
  for (int i = 0; i < 4; ++i) {
    v[i] = row[l + i * 64];
    #pragma unroll
    for (int j = 0; j < 4; ++j) { s += v[i][j]; sq += v[i][j] * v[i][j]; }
  }
  #pragma unroll
  for (int off = 1; off < 64; off <<= 1) {
    s  += __shfl_xor(s, off);
    sq += __shfl_xor(sq, off);
  }
  float mu  = s * (1.0f / DMODEL);
  float var = sq * (1.0f / DMODEL) - mu * mu;
  float rs  = rsqrtf(var + 1e-5f);

  float acc[NE] = {0.f, 0.f, 0.f, 0.f, 0.f, 0.f, 0.f, 0.f};
  #pragma unroll
  for (int i = 0; i < 4; ++i) {
    int base = (l + i * 64) * 4;
    #pragma unroll
    for (int j = 0; j < 4; ++j) {
      int idx = base + j;
      float xn = (v[i][j] - mu) * rs * gam[idx] + bet[idx];
      const f32x4* wr0 = (const f32x4*)(wrt + idx * NE);
      f32x4 w0 = wr0[0], w1v = wr0[1];
      acc[0] += xn * w0[0]; acc[1] += xn * w0[1];
      acc[2] += xn * w0[2]; acc[3] += xn * w0[3];
      acc[4] += xn * w1v[0]; acc[5] += xn * w1v[1];
      acc[6] += xn * w1v[2]; acc[7] += xn * w1v[3];
    }
  }
  #pragma unroll
  for (int e = 0; e < NE; ++e) {
    #pragma unroll
    for (int off = 1; off < 64; off <<= 1) acc[e] += __shfl_xor(acc[e], off);
  }
  if (l == 0) {
    int e0 = 0; float m0v = acc[0];
    #pragma unroll
    for (int e = 1; e < NE; ++e) if (acc[e] > m0v) { m0v = acc[e]; e0 = e; }
    int e1 = -1; float m1v = -1e30f;
    #pragma unroll
    for (int e = 0; e < NE; ++e) if (e != e0 && acc[e] > m1v) { m1v = acc[e]; e1 = e; }
    float r = __expf(m1v - m0v);      // p1/p0
    float g0 = 1.0f / (1.0f + r);
    float g1 = r * g0;
    t_e[t] = make_int2(e0, e1);
    t_g[t] = make_float2(g0, g1);
    atomicAdd(&ctrl[C_CNT + e0], 1);
    atomicAdd(&ctrl[C_CNT + e1], 1);
  }
}

// ---------------------------------------------------------------------------
// Scan: per-expert 128-padded slot bases + m-tile table. Single thread.
// ---------------------------------------------------------------------------
__global__ void scan_kernel(int* __restrict__ ctrl)
{
  if (threadIdx.x == 0 && blockIdx.x == 0) {
    int b = 0, m = 0;
    for (int e = 0; e < NE; ++e) {
      ctrl[C_BASE + e] = b;
      int pc = (ctrl[C_CNT + e] + 127) & ~127;
      int nt = pc >> 7;
      for (int i = 0; i < nt; ++i) {
        ctrl[C_MTE + m] = e;
        ctrl[C_MTS + m] = b + (i << 7);
        ++m;
      }
      b += pc;
    }
    ctrl[C_NMT] = m;
  }
}

// ---------------------------------------------------------------------------
// Gather: fill slot -> (token, gate). One thread per token.
// ---------------------------------------------------------------------------
__global__ __launch_bounds__(256) void gather_kernel(
    int* __restrict__ ctrl,
    const int2* __restrict__ t_e,
    const float2* __restrict__ t_g,
    int* __restrict__ slot_token,
    float* __restrict__ slot_gate)
{
  int t = blockIdx.x * 256 + threadIdx.x;
  int2 e = t_e[t];
  float2 g = t_g[t];
  int p0 = atomicAdd(&ctrl[C_FILL + e.x], 1);
  int s0 = ctrl[C_BASE + e.x] + p0;
  slot_token[s0] = t; slot_gate[s0] = g.x;
  int p1 = atomicAdd(&ctrl[C_FILL + e.y], 1);
  int s1 = ctrl[C_BASE + e.y] + p1;
  slot_token[s1] = t; slot_gate[s1] = g.y;
}

// ---------------------------------------------------------------------------
// Sparse MoE w1 GEMM: Hs[slot] = gelu(h2[token(slot)] @ w1[e] + b1[e]).
// 128x128 tile, BK=32, 4 waves, A-rows gathered via slot_token.
// ---------------------------------------------------------------------------
__global__ __launch_bounds__(256) void moe_w1(
    const unsigned short* __restrict__ h2,
    const float* __restrict__ w1,
    const float* __restrict__ b1,
    const int* __restrict__ ctrl,
    const int* __restrict__ slot_token,
    unsigned short* __restrict__ Hs)
{
  int mt = blockIdx.y;
  if (mt >= ctrl[C_NMT]) return;
  int e = ctrl[C_MTE + mt];
  int slot0 = ctrl[C_MTS + mt];
  const float* Bm = w1 + (size_t)e * DMODEL * DFF;
  const float* bias = b1 + (size_t)e * DFF;
  const int N = DFF, K = DMODEL;

  __shared__ unsigned short Al[128][40];
  __shared__ unsigned short Bl[128][40];
  __shared__ int tokrow[128];
  int tid = threadIdx.x;
  if (tid < 128) {
    int tk = slot_token[slot0 + tid];
    tokrow[tid] = tk < 0 ? 0 : tk;
  }
  int l = tid & 63, w = tid >> 6;
  int wr = w >> 1, wc = w & 1;
  int n0 = blockIdx.x * 128;

  const f32x4 z = {0.f, 0.f, 0.f, 0.f};
  f32x4 acc[4][4];
  #pragma unroll
  for (int i = 0; i < 4; ++i)
    #pragma unroll
    for (int j = 0; j < 4; ++j) acc[i][j] = z;

  for (int k0 = 0; k0 < K; k0 += 32) {
    __syncthreads();
    for (int c = tid; c < 512; c += 256) {
      int row = c >> 2, kc = (c & 3) << 3;
      uint4v v = *(const uint4v*)(h2 + (size_t)tokrow[row] * DMODEL + k0 + kc);
      *(uint4v*)(&Al[row][kc]) = v;
    }
    for (int c = tid; c < 1024; c += 256) {
      int k = c >> 5, nc = (c & 31) << 2;
      f32x4 v = *(const f32x4*)(Bm + (size_t)(k0 + k) * N + n0 + nc);
      Bl[nc + 0][k] = f2bf(v[0]);
      Bl[nc + 1][k] = f2bf(v[1]);
      Bl[nc + 2][k] = f2bf(v[2]);
      Bl[nc + 3][k] = f2bf(v[3]);
    }
    __syncthreads();

    short8 af[4], bfr[4];
    #pragma unroll
    for (int m = 0; m < 4; ++m)
      af[m] = *(const short8*)(&Al[wr * 64 + m * 16 + (l & 15)][(l >> 4) << 3]);
    #pragma unroll
    for (int n = 0; n < 4; ++n)
      bfr[n] = *(const short8*)(&Bl[wc * 64 + n * 16 + (l & 15)][(l >> 4) << 3]);
    #pragma unroll
    for (int m = 0; m < 4; ++m)
      #pragma unroll
      for (int n = 0; n < 4; ++n)
        acc[m][n] = __builtin_amdgcn_mfma_f32_16x16x32_bf16(af[m], bfr[n], acc[m][n], 0, 0, 0);
  }

  int rbase = wr * 64 + ((l >> 4) << 2);
  int cbase = n0 + wc * 64 + (l & 15);
  #pragma unroll
  for (int n = 0; n < 4; ++n) {
    int col = cbase + n * 16;
    float bv = bias[col];
    #pragma unroll
    for (int m = 0; m < 4; ++m) {
      #pragma unroll
      for (int r = 0; r < 4; ++r) {
        int srow = slot0 + rbase + m * 16 + r;
        float v = acc[m][n][r] + bv;
        v = 0.5f * v * (1.0f + erff(v * 0.70710678118654752f));
        Hs[(size_t)srow * DFF + col] = f2bf(v);
      }
    }
  }
}

// ---------------------------------------------------------------------------
// Sparse MoE w2 GEMM: ffn[token(slot)] += gate(slot) * (Hs[slot] @ w2[e] + b2[e])
// ---------------------------------------------------------------------------
__global__ __launch_bounds__(256) void moe_w2(
    const unsigned short* __restrict__ Hs,
    const float* __restrict__ w2,
    const float* __restrict__ b2,
    const int* __restrict__ ctrl,
    const int* __restrict__ slot_token,
    const float* __restrict__ slot_gate,
    float* __restrict__ ffn)
{
  int mt = blockIdx.y;
  if (mt >= ctrl[C_NMT]) return;
  int e = ctrl[C_MTE + mt];
  int slot0 = ctrl[C_MTS + mt];
  const float* Bm = w2 + (size_t)e * DFF * DMODEL;
  const float* bias = b2 + (size_t)e * DMODEL;
  const int N = DMODEL, K = DFF;

  __shared__ unsigned short Al[128][40];
  __shared__ unsigned short Bl[128][40];
  int tid = threadIdx.x;
  int l = tid & 63, w = tid >> 6;
  int wr = w >> 1, wc = w & 1;
  int n0 = blockIdx.x * 128;

  const f32x4 z = {0.f, 0.f, 0.f, 0.f};
  f32x4 acc[4][4];
  #pragma unroll
  for (int i = 0; i < 4; ++i)
    #pragma unroll
    for (int j = 0; j < 4; ++j) acc[i][j] = z;

  for (int k0 = 0; k0 < K; k0 += 32) {
    __syncthreads();
    for (int c = tid; c < 512; c += 256) {
      int row = c >> 2, kc = (c & 3) << 3;
      uint4v v = *(const uint4v*)(Hs + (size_t)(slot0 + row) * DFF + k0 + kc);
      *(uint4v*)(&Al[row][kc]) = v;
    }
    for (int c = tid; c < 1024; c += 256) {
      int k = c >> 5, nc = (c & 31) << 2;
      f32x4 v = *(const f32x4*)(Bm + (size_t)(k0 + k) * N + n0 + nc);
      Bl[nc + 0][k] = f2bf(v[0]);
      Bl[nc + 1][k] = f2bf(v[1]);
      Bl[nc + 2][k] = f2bf(v[2]);
      Bl[nc + 3][k] = f2bf(v[3]);
    }
    __syncthreads();

    short8 af[4], bfr[4];
    #pragma unroll
    for (int m = 0; m < 4; ++m)
      af[m] = *(const short8*)(&Al[wr * 64 + m * 16 + (l & 15)][(l >> 4) << 3]);
    #pragma unroll
    for (int n = 0; n < 4; ++n)
      bfr[n] = *(const short8*)(&Bl[wc * 64 + n * 16 + (l & 15)][(l >> 4) << 3]);
    #pragma unroll
    for (int m = 0; m < 4; ++m)
      #pragma unroll
      for (int n = 0; n < 4; ++n)
        acc[m][n] = __builtin_amdgcn_mfma_f32_16x16x32_bf16(af[m], bfr[n], acc[m][n], 0, 0, 0);
  }

  int rbase = wr * 64 + ((l >> 4) << 2);
  int cbase = n0 + wc * 64 + (l & 15);
  #pragma unroll
  for (int n = 0; n < 4; ++n) {
    int col = cbase + n * 16;
    float bv = bias[col];
    #pragma unroll
    for (int m = 0; m < 4; ++m) {
      #pragma unroll
      for (int r = 0; r < 4; ++r) {
        int srow = slot0 + rbase + m * 16 + r;
        int tok = slot_token[srow];
        if (tok >= 0) {
          float v = acc[m][n][r] + bv;
          atomicAdd(&ffn[(size_t)tok * DMODEL + col], slot_gate[srow] * v);
        }
      }
    }
  }
}

// ---------------------------------------------------------------------------
// out = x1 + ffn   (all fp32)
// ---------------------------------------------------------------------------
__global__ __launch_bounds__(256) void final_add(
    const float* __restrict__ x1,
    const float* __restrict__ ffn,
    float* __restrict__ out)
{
  int i = blockIdx.x * 256 + threadIdx.x;
  f32x4 xr = ((const f32x4*)x1)[i];
  f32x4 fr = ((const f32x4*)ffn)[i];
  f32x4 o;
  o[0] = xr[0] + fr[0];
  o[1] = xr[1] + fr[1];
  o[2] = xr[2] + fr[2];
  o[3] = xr[3] + fr[3];
  ((f32x4*)out)[i] = o;
}

// ---------------------------------------------------------------------------
extern "C" void kernel_launch(void* const* d_in, const int* in_sizes, int n_in,
                              void* d_out, int out_size, void* d_ws, size_t ws_size,
                              hipStream_t stream) {
  (void)in_sizes; (void)n_in; (void)out_size; (void)ws_size;
  const float* x     = (const float*)d_in[0];
  const float* ln1_g = (const float*)d_in[1];
  const float* ln1_b = (const float*)d_in[2];
  const float* ln2_g = (const float*)d_in[3];
  const float* ln2_b = (const float*)d_in[4];
  const float* wqkv  = (const float*)d_in[5];
  const float* bqkv  = (const float*)d_in[6];
  const float* wo    = (const float*)d_in[7];
  const float* bo    = (const float*)d_in[8];
  const float* wrt   = (const float*)d_in[9];
  const float* w1    = (const float*)d_in[10];
  const float* b1    = (const float*)d_in[11];
  const float* w2    = (const float*)d_in[12];
  const float* b2    = (const float*)d_in[13];
  float* out = (float*)d_out;

  char* ws = (char*)d_ws;
  size_t off = 0;
  auto alloc = [&](size_t bytes) -> void* {
    void* p = ws + off;
    off += (bytes + 255) & ~(size_t)255;
    return p;
  };
  float*          x1    = (float*)alloc((size_t)TTOK * DMODEL * 4);
  unsigned short* h2    = (unsigned short*)alloc((size_t)TTOK * DMODEL * 2);
  int*            ctrl  = (int*)alloc(1024);
  int2*           t_e   = (int2*)alloc((size_t)TTOK * 8);
  float2*         t_g   = (float2*)alloc((size_t)TTOK * 8);
  int*            slot_token = (int*)alloc((size_t)SLOT_MAX * 4);
  float*          slot_gate  = (float*)alloc((size_t)SLOT_MAX * 4);
  // P1: h -> ctx -> ffn (16.8 MB, lifetimes disjoint)
  float*          P1    = (float*)alloc((size_t)TTOK * DMODEL * 4);
  // P2: qkv (50.3 MB) -> Hslots (75.5 MB), lifetimes disjoint
  char*           P2    = (char*)alloc((size_t)SLOT_MAX * DFF * 2);
  float*          h    = P1;
  float*          qkv  = (float*)P2;
  float*          ctx  = P1;
  float*          ffn  = P1;
  unsigned short* Hs   = (unsigned short*)P2;

  // 0) zero control counters, mark all slots invalid
  hipMemsetAsync(ctrl, 0, 16 * 4, stream);                 // CNT + FILL
  hipMemsetAsync(slot_token, 0xFF, (size_t)SLOT_MAX * 4, stream);

  // 1) h = LN1(x)                       (fp32)
  ln_kernel<false><<<TTOK, 256, 0, stream>>>(x, ln1_g, ln1_b, h, nullptr);
  // 2) qkv = h @ wqkv + bqkv            (fp32 SGEMM — precision-critical path)
  sgemm64<0><<<dim3(3 * DMODEL / 64, TTOK / 64), 256, 0, stream>>>(
      h, wqkv, bqkv, nullptr, qkv, TTOK, 3 * DMODEL, DMODEL);
  // 3) ctx = causal attention           (fp32, 4 threads/q-row)
  attn4_kernel<<<dim3(SEQ / 64, NB * NH), 256, 0, stream>>>(qkv, ctx);
  // 4) x1 = x + ctx @ wo + bo           (fp32 SGEMM)
  sgemm64<1><<<dim3(DMODEL / 64, TTOK / 64), 256, 0, stream>>>(
      ctx, wo, bo, x, x1, TTOK, DMODEL, DMODEL);
  // 5) h2 = LN2(x1)                     (bf16, feeds MoE MFMA GEMMs)
  ln_kernel<true><<<TTOK, 256, 0, stream>>>(x1, ln2_g, ln2_b, nullptr, h2);
  // 6) router -> top2 + counts; scan -> slot bases/tiles; gather -> slot map
  router_kernel<<<TTOK / 4, 256, 0, stream>>>(x1, ln2_g, ln2_b, wrt, ctrl, t_e, t_g);
  scan_kernel<<<1, 64, 0, stream>>>(ctrl);
  gather_kernel<<<TTOK / 256, 256, 0, stream>>>(ctrl, t_e, t_g, slot_token, slot_gate);
  // 7) sparse MoE
  hipMemsetAsync(ffn, 0, (size_t)TTOK * DMODEL * 4, stream);
  moe_w1<<<dim3(DFF / 128, MT_MAX), 256, 0, stream>>>(
      h2, w1, b1, ctrl, slot_token, Hs);
  moe_w2<<<dim3(DMODEL / 128, MT_MAX), 256, 0, stream>>>(
      Hs, w2, b2, ctrl, slot_token, slot_gate, ffn);
  // 8) out = x1 + ffn  (fp32)
  final_add<<<(TTOK * DMODEL / 4) / 256, 256, 0, stream>>>(x1, ffn, out);
}

// Round 5
// 2133.628 us; speedup vs baseline: 2.9887x; 1.1011x over previous
//
#include <hip/hip_runtime.h>
#include <hip/hip_bf16.h>
#include <math.h>

// Problem constants
#define NB    2
#define SEQ   2048
#define DMODEL 1024
#define NH    16
#define HDIM  64
#define NE    8
#define DFF   4096
#define TTOK  4096   // NB*SEQ

#define MT_MAX   72     // worst-case m-tiles over all experts (128-padded)
#define SLOT_MAX 9216   // worst-case padded slot count

// ctrl block layout (ints)
#define C_CNT  0    // [8]  per-expert token counts
#define C_FILL 8    // [8]  gather fill cursors
#define C_BASE 16   // [8]  per-expert slot base
#define C_NMT  24   // [1]  number of m-tiles
#define C_MTE  32   // [72] m-tile -> expert
#define C_MTS  104  // [72] m-tile -> slot base

typedef __attribute__((ext_vector_type(8))) short short8;
typedef __attribute__((ext_vector_type(4))) float f32x4;
typedef __attribute__((ext_vector_type(4))) unsigned int uint4v;

static __device__ __forceinline__ unsigned short f2bf(float f) {
  unsigned int x = __float_as_uint(f);
  unsigned int r = (x + 0x7FFFu + ((x >> 16) & 1u)) >> 16;
  return (unsigned short)r;
}

// ---------------------------------------------------------------------------
// LayerNorm: one block (256 thr) per token. fp32 in. BF16OUT selects output.
// ---------------------------------------------------------------------------
template<bool BF16OUT>
__global__ __launch_bounds__(256) void ln_kernel(
    const float* __restrict__ x,
    const float* __restrict__ gam,
    const float* __restrict__ bet,
    float* __restrict__ outf,
    unsigned short* __restrict__ outb)
{
  int t = blockIdx.x, tid = threadIdx.x;
  f32x4 v = ((const f32x4*)(x + (size_t)t * DMODEL))[tid];
  float s  = v[0] + v[1] + v[2] + v[3];
  float sq = v[0]*v[0] + v[1]*v[1] + v[2]*v[2] + v[3]*v[3];
  #pragma unroll
  for (int off = 1; off < 64; off <<= 1) {
    s  += __shfl_xor(s, off);
    sq += __shfl_xor(sq, off);
  }
  __shared__ float red[8];
  int w = tid >> 6, l = tid & 63;
  if (l == 0) { red[w] = s; red[4 + w] = sq; }
  __syncthreads();
  s  = red[0] + red[1] + red[2] + red[3];
  sq = red[4] + red[5] + red[6] + red[7];
  float mu  = s * (1.0f / DMODEL);
  float var = sq * (1.0f / DMODEL) - mu * mu;
  float rs  = rsqrtf(var + 1e-5f);
  f32x4 g = ((const f32x4*)gam)[tid];
  f32x4 b = ((const f32x4*)bet)[tid];
  float r0 = (v[0] - mu) * rs * g[0] + b[0];
  float r1 = (v[1] - mu) * rs * g[1] + b[1];
  float r2 = (v[2] - mu) * rs * g[2] + b[2];
  float r3 = (v[3] - mu) * rs * g[3] + b[3];
  if constexpr (BF16OUT) {
    ushort4 o; o.x = f2bf(r0); o.y = f2bf(r1); o.z = f2bf(r2); o.w = f2bf(r3);
    ((ushort4*)(outb + (size_t)t * DMODEL))[tid] = o;
  } else {
    f32x4 o = {r0, r1, r2, r3};
    ((f32x4*)(outf + (size_t)t * DMODEL))[tid] = o;
  }
}

// ---------------------------------------------------------------------------
// fp32 vector SGEMM, 128x128 tile, BK=16, 256 threads, 8x8 per thread.
// EPI 0: C = A@B + bias.  EPI 1: C = A@B + bias + resid.
// ---------------------------------------------------------------------------
template<int EPI>
__global__ __launch_bounds__(256) void sgemm128(
    const float* __restrict__ A, const float* __restrict__ B,
    const float* __restrict__ bias, const float* __restrict__ resid,
    float* __restrict__ C, int M, int N, int K)
{
  __shared__ float As[16][132];
  __shared__ float Bs[16][132];
  int tid = threadIdx.x;
  int tx = tid & 15, ty = tid >> 4;
  int m0 = blockIdx.y * 128, n0 = blockIdx.x * 128;
  float c[8][8] = {};
  for (int k0 = 0; k0 < K; k0 += 16) {
    __syncthreads();
    #pragma unroll
    for (int i = 0; i < 2; ++i) {              // A: 128 rows x 16 k, transposed
      int ch = tid + i * 256;
      int row = ch >> 2, kc = (ch & 3) << 2;
      f32x4 v = *(const f32x4*)(A + (size_t)(m0 + row) * K + k0 + kc);
      As[kc + 0][row] = v[0]; As[kc + 1][row] = v[1];
      As[kc + 2][row] = v[2]; As[kc + 3][row] = v[3];
    }
    #pragma unroll
    for (int i = 0; i < 2; ++i) {              // B: 16 k x 128 n
      int ch = tid + i * 256;
      int k = ch >> 5, nc = (ch & 31) << 2;
      *(f32x4*)(&Bs[k][nc]) = *(const f32x4*)(B + (size_t)(k0 + k) * N + n0 + nc);
    }
    __syncthreads();
    #pragma unroll
    for (int k = 0; k < 16; ++k) {
      f32x4 a0 = *(const f32x4*)(&As[k][ty * 8]);
      f32x4 a1 = *(const f32x4*)(&As[k][ty * 8 + 4]);
      f32x4 b0 = *(const f32x4*)(&Bs[k][tx * 8]);
      f32x4 b1 = *(const f32x4*)(&Bs[k][tx * 8 + 4]);
      #pragma unroll
      for (int i = 0; i < 4; ++i) {
        #pragma unroll
        for (int j = 0; j < 4; ++j) {
          c[i][j]         = fmaf(a0[i], b0[j], c[i][j]);
          c[i][j + 4]     = fmaf(a0[i], b1[j], c[i][j + 4]);
          c[i + 4][j]     = fmaf(a1[i], b0[j], c[i + 4][j]);
          c[i + 4][j + 4] = fmaf(a1[i], b1[j], c[i + 4][j + 4]);
        }
      }
    }
  }
  float bv[8];
  #pragma unroll
  for (int j = 0; j < 8; ++j) bv[j] = bias[n0 + tx * 8 + j];
  #pragma unroll
  for (int i = 0; i < 8; ++i) {
    int row = m0 + ty * 8 + i;
    size_t base = (size_t)row * N + n0 + tx * 8;
    f32x4 r0, r1;
    #pragma unroll
    for (int j = 0; j < 4; ++j) { r0[j] = c[i][j] + bv[j]; r1[j] = c[i][j + 4] + bv[j + 4]; }
    if constexpr (EPI == 1) {
      f32x4 e0 = *(const f32x4*)(resid + base);
      f32x4 e1 = *(const f32x4*)(resid + base + 4);
      r0 += e0; r1 += e1;
    }
    *(f32x4*)(C + base) = r0;
    *(f32x4*)(C + base + 4) = r1;
  }
}

// ---------------------------------------------------------------------------
// Flash chunk step: one 64-row K/V tile against one q-row slice (16 dims).
// ---------------------------------------------------------------------------
__device__ __forceinline__ void flash_chunk(
    const float (*Kl)[68], const float (*Vl)[68],
    const f32x4* __restrict__ q, f32x4* __restrict__ o,
    float& mrun, float& lrun, int jmax, int d0)
{
  for (int jb = 0; jb <= jmax; jb += 16) {
    float sv[16];
    float cm = -1e30f;
    #pragma unroll
    for (int j = 0; j < 16; ++j) {
      int jj = jb + j;
      const f32x4* kr = (const f32x4*)(&Kl[jj][d0]);
      f32x4 a0 = kr[0], a1 = kr[1], a2 = kr[2], a3 = kr[3];
      float d =
        q[0][0]*a0[0] + q[0][1]*a0[1] + q[0][2]*a0[2] + q[0][3]*a0[3] +
        q[1][0]*a1[0] + q[1][1]*a1[1] + q[1][2]*a1[2] + q[1][3]*a1[3] +
        q[2][0]*a2[0] + q[2][1]*a2[1] + q[2][2]*a2[2] + q[2][3]*a2[3] +
        q[3][0]*a3[0] + q[3][1]*a3[1] + q[3][2]*a3[2] + q[3][3]*a3[3];
      d += __shfl_xor(d, 1);
      d += __shfl_xor(d, 2);
      sv[j] = (jj <= jmax) ? d * 0.125f : -1e30f;
      cm = fmaxf(cm, sv[j]);
    }
    float nm = fmaxf(mrun, cm);
    float sc = __expf(mrun - nm);
    lrun *= sc;
    o[0] = o[0] * sc; o[1] = o[1] * sc; o[2] = o[2] * sc; o[3] = o[3] * sc;
    #pragma unroll
    for (int j = 0; j < 16; ++j) {
      float p = __expf(sv[j] - nm);
      lrun += p;
      const f32x4* vr = (const f32x4*)(&Vl[jb + j][d0]);
      o[0] += p * vr[0]; o[1] += p * vr[1]; o[2] += p * vr[2]; o[3] += p * vr[3];
    }
    mrun = nm;
  }
}

// ---------------------------------------------------------------------------
// Causal flash attention, fp32, 4 threads/q-row, causal-fold load balancing.
// Block handles q-tile pair (bx, 31-bx): uniform 33 tile-steps per block.
// Grid (16, B*H); block 256 = 64 q-rows x 4 dim-slices of 16.
// ---------------------------------------------------------------------------
__global__ __launch_bounds__(256) void attn_bal(
    const float* __restrict__ qkv,
    float* __restrict__ ctx)
{
  __shared__ float Kl[64][68];
  __shared__ float Vl[64][68];
  int bh = blockIdx.y;
  int b = bh >> 4, h = bh & 15;
  int bx = blockIdx.x;                 // 0..15
  int tid = threadIdx.x;
  int ql = tid >> 2, d0 = (tid & 3) * 16;
  int qtA = bx, qtB = 31 - bx;
  int qA = qtA * 64 + ql, qB = qtB * 64 + ql;
  const int bS = b * SEQ;

  f32x4 qa[4], qb[4], oa[4], ob[4];
  {
    const f32x4* pa = (const f32x4*)(qkv + (size_t)(bS + qA) * 3072 + h * HDIM + d0);
    const f32x4* pb = (const f32x4*)(qkv + (size_t)(bS + qB) * 3072 + h * HDIM + d0);
    #pragma unroll
    for (int i = 0; i < 4; ++i) { qa[i] = pa[i]; qb[i] = pb[i]; }
  }
  const f32x4 z = {0.f, 0.f, 0.f, 0.f};
  #pragma unroll
  for (int i = 0; i < 4; ++i) { oa[i] = z; ob[i] = z; }
  float mA = -1e30f, lA = 0.f, mB = -1e30f, lB = 0.f;

  for (int kt = 0; kt <= qtB; ++kt) {
    __syncthreads();
    {
      int r = tid >> 2, cc = (tid & 3) * 16;
      size_t gk = ((size_t)(bS + kt * 64 + r)) * 3072 + DMODEL + h * HDIM + cc;
      const f32x4* kp = (const f32x4*)(qkv + gk);
      const f32x4* vp = (const f32x4*)(qkv + gk + DMODEL);
      f32x4* kd = (f32x4*)(&Kl[r][cc]);
      f32x4* vd = (f32x4*)(&Vl[r][cc]);
      kd[0] = kp[0]; kd[1] = kp[1]; kd[2] = kp[2]; kd[3] = kp[3];
      vd[0] = vp[0]; vd[1] = vp[1]; vd[2] = vp[2]; vd[3] = vp[3];
    }
    __syncthreads();
    if (kt <= qtA) {
      int jm = qA - kt * 64; if (jm > 63) jm = 63;
      flash_chunk(Kl, Vl, qa, oa, mA, lA, jm, d0);
    }
    {
      int jm = qB - kt * 64; if (jm > 63) jm = 63;
      flash_chunk(Kl, Vl, qb, ob, mB, lB, jm, d0);
    }
  }
  {
    float inv = 1.0f / lA;
    float* orow = ctx + ((size_t)(bS + qA)) * DMODEL + h * HDIM + d0;
    #pragma unroll
    for (int i = 0; i < 4; ++i) ((f32x4*)orow)[i] = oa[i] * inv;
  }
  {
    float inv = 1.0f / lB;
    float* orow = ctx + ((size_t)(bS + qB)) * DMODEL + h * HDIM + d0;
    #pragma unroll
    for (int i = 0; i < 4; ++i) ((f32x4*)orow)[i] = ob[i] * inv;
  }
}

// ---------------------------------------------------------------------------
// Router (fp32): one wave per token. Recomputes LN2 from x1, logits, top-2.
// ---------------------------------------------------------------------------
__global__ __launch_bounds__(256) void router_kernel(
    const float* __restrict__ x1,
    const float* __restrict__ gam,
    const float* __restrict__ bet,
    const float* __restrict__ wrt,
    int* __restrict__ ctrl,
    int2* __restrict__ t_e,
    float2* __restrict__ t_g)
{
  int w = threadIdx.x >> 6, l = threadIdx.x & 63;
  int t = blockIdx.x * 4 + w;
  const f32x4* row = (const f32x4*)(x1 + (size_t)t * DMODEL);
  f32x4 v[4];
  float s = 0.f, sq = 0.f;
  #pragma unroll
  for (int i = 0; i < 4; ++i) {
    v[i] = row[l + i * 64];
    #pragma unroll
    for (int j = 0; j < 4; ++j) { s += v[i][j]; sq += v[i][j] * v[i][j]; }
  }
  #pragma unroll
  for (int off = 1; off < 64; off <<= 1) {
    s  += __shfl_xor(s, off);
    sq += __shfl_xor(sq, off);
  }
  float mu  = s * (1.0f / DMODEL);
  float var = sq * (1.0f / DMODEL) - mu * mu;
  float rs  = rsqrtf(var + 1e-5f);

  float acc[NE] = {0.f, 0.f, 0.f, 0.f, 0.f, 0.f, 0.f, 0.f};
  #pragma unroll
  for (int i = 0; i < 4; ++i) {
    int base = (l + i * 64) * 4;
    #pragma unroll
    for (int j = 0; j < 4; ++j) {
      int idx = base + j;
      float xn = (v[i][j] - mu) * rs * gam[idx] + bet[idx];
      const f32x4* wr0 = (const f32x4*)(wrt + idx * NE);
      f32x4 w0 = wr0[0], w1v = wr0[1];
      acc[0] += xn * w0[0]; acc[1] += xn * w0[1];
      acc[2] += xn * w0[2]; acc[3] += xn * w0[3];
      acc[4] += xn * w1v[0]; acc[5] += xn * w1v[1];
      acc[6] += xn * w1v[2]; acc[7] += xn * w1v[3];
    }
  }
  #pragma unroll
  for (int e = 0; e < NE; ++e) {
    #pragma unroll
    for (int off = 1; off < 64; off <<= 1) acc[e] += __shfl_xor(acc[e], off);
  }
  if (l == 0) {
    int e0 = 0; float m0v = acc[0];
    #pragma unroll
    for (int e = 1; e < NE; ++e) if (acc[e] > m0v) { m0v = acc[e]; e0 = e; }
    int e1 = -1; float m1v = -1e30f;
    #pragma unroll
    for (int e = 0; e < NE; ++e) if (e != e0 && acc[e] > m1v) { m1v = acc[e]; e1 = e; }
    float r = __expf(m1v - m0v);
    float g0 = 1.0f / (1.0f + r);
    float g1 = r * g0;
    t_e[t] = make_int2(e0, e1);
    t_g[t] = make_float2(g0, g1);
    atomicAdd(&ctrl[C_CNT + e0], 1);
    atomicAdd(&ctrl[C_CNT + e1], 1);
  }
}

// ---------------------------------------------------------------------------
// Scan: per-expert 128-padded slot bases + m-tile table. Single thread.
// ---------------------------------------------------------------------------
__global__ void scan_kernel(int* __restrict__ ctrl)
{
  if (threadIdx.x == 0 && blockIdx.x == 0) {
    int b = 0, m = 0;
    for (int e = 0; e < NE; ++e) {
      ctrl[C_BASE + e] = b;
      int pc = (ctrl[C_CNT + e] + 127) & ~127;
      int nt = pc >> 7;
      for (int i = 0; i < nt; ++i) {
        ctrl[C_MTE + m] = e;
        ctrl[C_MTS + m] = b + (i << 7);
        ++m;
      }
      b += pc;
    }
    ctrl[C_NMT] = m;
  }
}

// ---------------------------------------------------------------------------
// Gather: fill slot -> (token, gate). One thread per token.
// ---------------------------------------------------------------------------
__global__ __launch_bounds__(256) void gather_kernel(
    int* __restrict__ ctrl,
    const int2* __restrict__ t_e,
    const float2* __restrict__ t_g,
    int* __restrict__ slot_token,
    float* __restrict__ slot_gate)
{
  int t = blockIdx.x * 256 + threadIdx.x;
  int2 e = t_e[t];
  float2 g = t_g[t];
  int p0 = atomicAdd(&ctrl[C_FILL + e.x], 1);
  int s0 = ctrl[C_BASE + e.x] + p0;
  slot_token[s0] = t; slot_gate[s0] = g.x;
  int p1 = atomicAdd(&ctrl[C_FILL + e.y], 1);
  int s1 = ctrl[C_BASE + e.y] + p1;
  slot_token[s1] = t; slot_gate[s1] = g.y;
}

// ---------------------------------------------------------------------------
// Sparse MoE w1 GEMM: Hs[slot] = gelu(h2[token(slot)] @ w1[e] + b1[e]).
// ---------------------------------------------------------------------------
__global__ __launch_bounds__(256) void moe_w1(
    const unsigned short* __restrict__ h2,
    const float* __restrict__ w1,
    const float* __restrict__ b1,
    const int* __restrict__ ctrl,
    const int* __restrict__ slot_token,
    unsigned short* __restrict__ Hs)
{
  int mt = blockIdx.y;
  if (mt >= ctrl[C_NMT]) return;
  int e = ctrl[C_MTE + mt];
  int slot0 = ctrl[C_MTS + mt];
  const float* Bm = w1 + (size_t)e * DMODEL * DFF;
  const float* bias = b1 + (size_t)e * DFF;
  const int N = DFF, K = DMODEL;

  __shared__ unsigned short Al[128][40];
  __shared__ unsigned short Bl[128][40];
  __shared__ int tokrow[128];
  int tid = threadIdx.x;
  if (tid < 128) {
    int tk = slot_token[slot0 + tid];
    tokrow[tid] = tk < 0 ? 0 : tk;
  }
  int l = tid & 63, w = tid >> 6;
  int wr = w >> 1, wc = w & 1;
  int n0 = blockIdx.x * 128;

  const f32x4 z = {0.f, 0.f, 0.f, 0.f};
  f32x4 acc[4][4];
  #pragma unroll
  for (int i = 0; i < 4; ++i)
    #pragma unroll
    for (int j = 0; j < 4; ++j) acc[i][j] = z;

  for (int k0 = 0; k0 < K; k0 += 32) {
    __syncthreads();
    for (int c = tid; c < 512; c += 256) {
      int row = c >> 2, kc = (c & 3) << 3;
      uint4v v = *(const uint4v*)(h2 + (size_t)tokrow[row] * DMODEL + k0 + kc);
      *(uint4v*)(&Al[row][kc]) = v;
    }
    for (int c = tid; c < 1024; c += 256) {
      int k = c >> 5, nc = (c & 31) << 2;
      f32x4 v = *(const f32x4*)(Bm + (size_t)(k0 + k) * N + n0 + nc);
      Bl[nc + 0][k] = f2bf(v[0]);
      Bl[nc + 1][k] = f2bf(v[1]);
      Bl[nc + 2][k] = f2bf(v[2]);
      Bl[nc + 3][k] = f2bf(v[3]);
    }
    __syncthreads();

    short8 af[4], bfr[4];
    #pragma unroll
    for (int m = 0; m < 4; ++m)
      af[m] = *(const short8*)(&Al[wr * 64 + m * 16 + (l & 15)][(l >> 4) << 3]);
    #pragma unroll
    for (int n = 0; n < 4; ++n)
      bfr[n] = *(const short8*)(&Bl[wc * 64 + n * 16 + (l & 15)][(l >> 4) << 3]);
    #pragma unroll
    for (int m = 0; m < 4; ++m)
      #pragma unroll
      for (int n = 0; n < 4; ++n)
        acc[m][n] = __builtin_amdgcn_mfma_f32_16x16x32_bf16(af[m], bfr[n], acc[m][n], 0, 0, 0);
  }

  int rbase = wr * 64 + ((l >> 4) << 2);
  int cbase = n0 + wc * 64 + (l & 15);
  #pragma unroll
  for (int n = 0; n < 4; ++n) {
    int col = cbase + n * 16;
    float bv = bias[col];
    #pragma unroll
    for (int m = 0; m < 4; ++m) {
      #pragma unroll
      for (int r = 0; r < 4; ++r) {
        int srow = slot0 + rbase + m * 16 + r;
        float v = acc[m][n][r] + bv;
        v = 0.5f * v * (1.0f + erff(v * 0.70710678118654752f));
        Hs[(size_t)srow * DFF + col] = f2bf(v);
      }
    }
  }
}

// ---------------------------------------------------------------------------
// Sparse MoE w2 GEMM: ffn[token(slot)] += gate(slot) * (Hs[slot] @ w2[e] + b2[e])
// ---------------------------------------------------------------------------
__global__ __launch_bounds__(256) void moe_w2(
    const unsigned short* __restrict__ Hs,
    const float* __restrict__ w2,
    const float* __restrict__ b2,
    const int* __restrict__ ctrl,
    const int* __restrict__ slot_token,
    const float* __restrict__ slot_gate,
    float* __restrict__ ffn)
{
  int mt = blockIdx.y;
  if (mt >= ctrl[C_NMT]) return;
  int e = ctrl[C_MTE + mt];
  int slot0 = ctrl[C_MTS + mt];
  const float* Bm = w2 + (size_t)e * DFF * DMODEL;
  const float* bias = b2 + (size_t)e * DMODEL;
  const int N = DMODEL, K = DFF;

  __shared__ unsigned short Al[128][40];
  __shared__ unsigned short Bl[128][40];
  int tid = threadIdx.x;
  int l = tid & 63, w = tid >> 6;
  int wr = w >> 1, wc = w & 1;
  int n0 = blockIdx.x * 128;

  const f32x4 z = {0.f, 0.f, 0.f, 0.f};
  f32x4 acc[4][4];
  #pragma unroll
  for (int i = 0; i < 4; ++i)
    #pragma unroll
    for (int j = 0; j < 4; ++j) acc[i][j] = z;

  for (int k0 = 0; k0 < K; k0 += 32) {
    __syncthreads();
    for (int c = tid; c < 512; c += 256) {
      int row = c >> 2, kc = (c & 3) << 3;
      uint4v v = *(const uint4v*)(Hs + (size_t)(slot0 + row) * DFF + k0 + kc);
      *(uint4v*)(&Al[row][kc]) = v;
    }
    for (int c = tid; c < 1024; c += 256) {
      int k = c >> 5, nc = (c & 31) << 2;
      f32x4 v = *(const f32x4*)(Bm + (size_t)(k0 + k) * N + n0 + nc);
      Bl[nc + 0][k] = f2bf(v[0]);
      Bl[nc + 1][k] = f2bf(v[1]);
      Bl[nc + 2][k] = f2bf(v[2]);
      Bl[nc + 3][k] = f2bf(v[3]);
    }
    __syncthreads();

    short8 af[4], bfr[4];
    #pragma unroll
    for (int m = 0; m < 4; ++m)
      af[m] = *(const short8*)(&Al[wr * 64 + m * 16 + (l & 15)][(l >> 4) << 3]);
    #pragma unroll
    for (int n = 0; n < 4; ++n)
      bfr[n] = *(const short8*)(&Bl[wc * 64 + n * 16 + (l & 15)][(l >> 4) << 3]);
    #pragma unroll
    for (int m = 0; m < 4; ++m)
      #pragma unroll
      for (int n = 0; n < 4; ++n)
        acc[m][n] = __builtin_amdgcn_mfma_f32_16x16x32_bf16(af[m], bfr[n], acc[m][n], 0, 0, 0);
  }

  int rbase = wr * 64 + ((l >> 4) << 2);
  int cbase = n0 + wc * 64 + (l & 15);
  #pragma unroll
  for (int n = 0; n < 4; ++n) {
    int col = cbase + n * 16;
    float bv = bias[col];
    #pragma unroll
    for (int m = 0; m < 4; ++m) {
      #pragma unroll
      for (int r = 0; r < 4; ++r) {
        int srow = slot0 + rbase + m * 16 + r;
        int tok = slot_token[srow];
        if (tok >= 0) {
          float v = acc[m][n][r] + bv;
          atomicAdd(&ffn[(size_t)tok * DMODEL + col], slot_gate[srow] * v);
        }
      }
    }
  }
}

// ---------------------------------------------------------------------------
// out = x1 + ffn   (all fp32)
// ---------------------------------------------------------------------------
__global__ __launch_bounds__(256) void final_add(
    const float* __restrict__ x1,
    const float* __restrict__ ffn,
    float* __restrict__ out)
{
  int i = blockIdx.x * 256 + threadIdx.x;
  f32x4 xr = ((const f32x4*)x1)[i];
  f32x4 fr = ((const f32x4*)ffn)[i];
  f32x4 o;
  o[0] = xr[0] + fr[0];
  o[1] = xr[1] + fr[1];
  o[2] = xr[2] + fr[2];
  o[3] = xr[3] + fr[3];
  ((f32x4*)out)[i] = o;
}

// ---------------------------------------------------------------------------
extern "C" void kernel_launch(void* const* d_in, const int* in_sizes, int n_in,
                              void* d_out, int out_size, void* d_ws, size_t ws_size,
                              hipStream_t stream) {
  (void)in_sizes; (void)n_in; (void)out_size; (void)ws_size;
  const float* x     = (const float*)d_in[0];
  const float* ln1_g = (const float*)d_in[1];
  const float* ln1_b = (const float*)d_in[2];
  const float* ln2_g = (const float*)d_in[3];
  const float* ln2_b = (const float*)d_in[4];
  const float* wqkv  = (const float*)d_in[5];
  const float* bqkv  = (const float*)d_in[6];
  const float* wo    = (const float*)d_in[7];
  const float* bo    = (const float*)d_in[8];
  const float* wrt   = (const float*)d_in[9];
  const float* w1    = (const float*)d_in[10];
  const float* b1    = (const float*)d_in[11];
  const float* w2    = (const float*)d_in[12];
  const float* b2    = (const float*)d_in[13];
  float* out = (float*)d_out;

  char* ws = (char*)d_ws;
  size_t off = 0;
  auto alloc = [&](size_t bytes) -> void* {
    void* p = ws + off;
    off += (bytes + 255) & ~(size_t)255;
    return p;
  };
  float*          x1    = (float*)alloc((size_t)TTOK * DMODEL * 4);
  unsigned short* h2    = (unsigned short*)alloc((size_t)TTOK * DMODEL * 2);
  int*            ctrl  = (int*)alloc(1024);
  int2*           t_e   = (int2*)alloc((size_t)TTOK * 8);
  float2*         t_g   = (float2*)alloc((size_t)TTOK * 8);
  int*            slot_token = (int*)alloc((size_t)SLOT_MAX * 4);
  float*          slot_gate  = (float*)alloc((size_t)SLOT_MAX * 4);
  // P1: h -> ctx -> ffn (16.8 MB, lifetimes disjoint)
  float*          P1    = (float*)alloc((size_t)TTOK * DMODEL * 4);
  // P2: qkv (50.3 MB) -> Hslots (75.5 MB), lifetimes disjoint
  char*           P2    = (char*)alloc((size_t)SLOT_MAX * DFF * 2);
  float*          h    = P1;
  float*          qkv  = (float*)P2;
  float*          ctx  = P1;
  float*          ffn  = P1;
  unsigned short* Hs   = (unsigned short*)P2;

  // 0) zero control counters, mark all slots invalid
  hipMemsetAsync(ctrl, 0, 16 * 4, stream);
  hipMemsetAsync(slot_token, 0xFF, (size_t)SLOT_MAX * 4, stream);

  // 1) h = LN1(x)                       (fp32)
  ln_kernel<false><<<TTOK, 256, 0, stream>>>(x, ln1_g, ln1_b, h, nullptr);
  // 2) qkv = h @ wqkv + bqkv            (fp32 SGEMM — precision-critical path)
  sgemm128<0><<<dim3(3 * DMODEL / 128, TTOK / 128), 256, 0, stream>>>(
      h, wqkv, bqkv, nullptr, qkv, TTOK, 3 * DMODEL, DMODEL);
  // 3) ctx = causal attention           (fp32, causal-fold balanced)
  attn_bal<<<dim3(SEQ / 128, NB * NH), 256, 0, stream>>>(qkv, ctx);
  // 4) x1 = x + ctx @ wo + bo           (fp32 SGEMM)
  sgemm128<1><<<dim3(DMODEL / 128, TTOK / 128), 256, 0, stream>>>(
      ctx, wo, bo, x, x1, TTOK, DMODEL, DMODEL);
  // 5) h2 = LN2(x1)                     (bf16, feeds MoE MFMA GEMMs)
  ln_kernel<true><<<TTOK, 256, 0, stream>>>(x1, ln2_g, ln2_b, nullptr, h2);
  // 6) router -> top2 + counts; scan -> slot bases/tiles; gather -> slot map
  router_kernel<<<TTOK / 4, 256, 0, stream>>>(x1, ln2_g, ln2_b, wrt, ctrl, t_e, t_g);
  scan_kernel<<<1, 64, 0, stream>>>(ctrl);
  gather_kernel<<<TTOK / 256, 256, 0, stream>>>(ctrl, t_e, t_g, slot_token, slot_gate);
  // 7) sparse MoE
  hipMemsetAsync(ffn, 0, (size_t)TTOK * DMODEL * 4, stream);
  moe_w1<<<dim3(DFF / 128, MT_MAX), 256, 0, stream>>>(
      h2, w1, b1, ctrl, slot_token, Hs);
  moe_w2<<<dim3(DMODEL / 128, MT_MAX), 256, 0, stream>>>(
      Hs, w2, b2, ctrl, slot_token, slot_gate, ffn);
  // 8) out = x1 + ffn  (fp32)
  final_add<<<(TTOK * DMODEL / 4) / 256, 256, 0, stream>>>(x1, ffn, out);
}

// Round 6
// 1729.829 us; speedup vs baseline: 3.6864x; 1.2334x over previous
//
#include <hip/hip_runtime.h>
#include <hip/hip_bf16.h>
#include <math.h>

// Problem constants
#define NB    2
#define SEQ   2048
#define DMODEL 1024
#define NH    16
#define HDIM  64
#define NE    8
#define DFF   4096
#define TTOK  4096   // NB*SEQ

#define MT_MAX   72     // worst-case m-tiles over all experts (128-padded)
#define SLOT_MAX 9216   // worst-case padded slot count

// ctrl block layout (ints)
#define C_CNT  0
#define C_FILL 8
#define C_BASE 16
#define C_NMT  24
#define C_MTE  32
#define C_MTS  104

typedef __attribute__((ext_vector_type(8))) short short8;
typedef __attribute__((ext_vector_type(4))) float f32x4;
typedef __attribute__((ext_vector_type(4))) unsigned int uint4v;

static __device__ __forceinline__ unsigned short f2bf(float f) {
  unsigned int x = __float_as_uint(f);
  unsigned int r = (x + 0x7FFFu + ((x >> 16) & 1u)) >> 16;
  return (unsigned short)r;
}

// ---------------------------------------------------------------------------
// LayerNorm
// ---------------------------------------------------------------------------
template<bool BF16OUT>
__global__ __launch_bounds__(256) void ln_kernel(
    const float* __restrict__ x,
    const float* __restrict__ gam,
    const float* __restrict__ bet,
    float* __restrict__ outf,
    unsigned short* __restrict__ outb)
{
  int t = blockIdx.x, tid = threadIdx.x;
  f32x4 v = ((const f32x4*)(x + (size_t)t * DMODEL))[tid];
  float s  = v[0] + v[1] + v[2] + v[3];
  float sq = v[0]*v[0] + v[1]*v[1] + v[2]*v[2] + v[3]*v[3];
  #pragma unroll
  for (int off = 1; off < 64; off <<= 1) {
    s  += __shfl_xor(s, off);
    sq += __shfl_xor(sq, off);
  }
  __shared__ float red[8];
  int w = tid >> 6, l = tid & 63;
  if (l == 0) { red[w] = s; red[4 + w] = sq; }
  __syncthreads();
  s  = red[0] + red[1] + red[2] + red[3];
  sq = red[4] + red[5] + red[6] + red[7];
  float mu  = s * (1.0f / DMODEL);
  float var = sq * (1.0f / DMODEL) - mu * mu;
  float rs  = rsqrtf(var + 1e-5f);
  f32x4 g = ((const f32x4*)gam)[tid];
  f32x4 b = ((const f32x4*)bet)[tid];
  float r0 = (v[0] - mu) * rs * g[0] + b[0];
  float r1 = (v[1] - mu) * rs * g[1] + b[1];
  float r2 = (v[2] - mu) * rs * g[2] + b[2];
  float r3 = (v[3] - mu) * rs * g[3] + b[3];
  if constexpr (BF16OUT) {
    ushort4 o; o.x = f2bf(r0); o.y = f2bf(r1); o.z = f2bf(r2); o.w = f2bf(r3);
    ((ushort4*)(outb + (size_t)t * DMODEL))[tid] = o;
  } else {
    f32x4 o = {r0, r1, r2, r3};
    ((f32x4*)(outf + (size_t)t * DMODEL))[tid] = o;
  }
}

// ---------------------------------------------------------------------------
// fp32 vector SGEMM, 128x128 tile, BK=16, 8x8 per thread.
// ---------------------------------------------------------------------------
template<int EPI>
__global__ __launch_bounds__(256) void sgemm128(
    const float* __restrict__ A, const float* __restrict__ B,
    const float* __restrict__ bias, const float* __restrict__ resid,
    float* __restrict__ C, int M, int N, int K)
{
  __shared__ float As[16][132];
  __shared__ float Bs[16][132];
  int tid = threadIdx.x;
  int tx = tid & 15, ty = tid >> 4;
  int m0 = blockIdx.y * 128, n0 = blockIdx.x * 128;
  float c[8][8] = {};
  for (int k0 = 0; k0 < K; k0 += 16) {
    __syncthreads();
    #pragma unroll
    for (int i = 0; i < 2; ++i) {
      int ch = tid + i * 256;
      int row = ch >> 2, kc = (ch & 3) << 2;
      f32x4 v = *(const f32x4*)(A + (size_t)(m0 + row) * K + k0 + kc);
      As[kc + 0][row] = v[0]; As[kc + 1][row] = v[1];
      As[kc + 2][row] = v[2]; As[kc + 3][row] = v[3];
    }
    #pragma unroll
    for (int i = 0; i < 2; ++i) {
      int ch = tid + i * 256;
      int k = ch >> 5, nc = (ch & 31) << 2;
      *(f32x4*)(&Bs[k][nc]) = *(const f32x4*)(B + (size_t)(k0 + k) * N + n0 + nc);
    }
    __syncthreads();
    #pragma unroll
    for (int k = 0; k < 16; ++k) {
      f32x4 a0 = *(const f32x4*)(&As[k][ty * 8]);
      f32x4 a1 = *(const f32x4*)(&As[k][ty * 8 + 4]);
      f32x4 b0 = *(const f32x4*)(&Bs[k][tx * 8]);
      f32x4 b1 = *(const f32x4*)(&Bs[k][tx * 8 + 4]);
      #pragma unroll
      for (int i = 0; i < 4; ++i) {
        #pragma unroll
        for (int j = 0; j < 4; ++j) {
          c[i][j]         = fmaf(a0[i], b0[j], c[i][j]);
          c[i][j + 4]     = fmaf(a0[i], b1[j], c[i][j + 4]);
          c[i + 4][j]     = fmaf(a1[i], b0[j], c[i + 4][j]);
          c[i + 4][j + 4] = fmaf(a1[i], b1[j], c[i + 4][j + 4]);
        }
      }
    }
  }
  float bv[8];
  #pragma unroll
  for (int j = 0; j < 8; ++j) bv[j] = bias[n0 + tx * 8 + j];
  #pragma unroll
  for (int i = 0; i < 8; ++i) {
    int row = m0 + ty * 8 + i;
    size_t base = (size_t)row * N + n0 + tx * 8;
    f32x4 r0, r1;
    #pragma unroll
    for (int j = 0; j < 4; ++j) { r0[j] = c[i][j] + bv[j]; r1[j] = c[i][j + 4] + bv[j + 4]; }
    if constexpr (EPI == 1) {
      f32x4 e0 = *(const f32x4*)(resid + base);
      f32x4 e1 = *(const f32x4*)(resid + base + 4);
      r0 += e0; r1 += e1;
    }
    *(f32x4*)(C + base) = r0;
    *(f32x4*)(C + base + 4) = r1;
  }
}

// ---------------------------------------------------------------------------
// Causal flash attention, fp32, 4 q-rows per thread (LDS reads amortized 4x),
// causal-fold over 128-row q-tile pairs (p, 15-p). Grid (8, B*H), block 256
// = 64 row-slots x 4 dim-slices of 16. Defer-max online softmax (THR=8).
// ---------------------------------------------------------------------------
#define DOT4(q) ( \
  q[0][0]*k0v[0]+q[0][1]*k0v[1]+q[0][2]*k0v[2]+q[0][3]*k0v[3] + \
  q[1][0]*k1v[0]+q[1][1]*k1v[1]+q[1][2]*k1v[2]+q[1][3]*k1v[3] + \
  q[2][0]*k2v[0]+q[2][1]*k2v[1]+q[2][2]*k2v[2]+q[2][3]*k2v[3] + \
  q[3][0]*k3v[0]+q[3][1]*k3v[1]+q[3][2]*k3v[2]+q[3][3]*k3v[3] )

#define CMAX8(s) fmaxf(fmaxf(fmaxf(s[0],s[1]),fmaxf(s[2],s[3])), \
                       fmaxf(fmaxf(s[4],s[5]),fmaxf(s[6],s[7])))

#define UPD(cm, m, l, o) \
  if (cm > m + 8.0f) { float sc_ = __expf(m - cm); l *= sc_; \
    o[0] = o[0]*sc_; o[1] = o[1]*sc_; o[2] = o[2]*sc_; o[3] = o[3]*sc_; m = cm; }

#define PVROW(sarr, m, l, o) \
  { float p_ = __expf(sarr[j] - m); l += p_; \
    o[0] += p_*v0v; o[1] += p_*v1v; o[2] += p_*v2v; o[3] += p_*v3v; }

__device__ __forceinline__ void attn_load_tile(
    const float* __restrict__ qkv, float (*Kl)[68], float (*Vl)[68],
    int bS, int h, int kt, int tid)
{
  int r = tid >> 2, cc = (tid & 3) * 16;
  size_t gk = ((size_t)(bS + kt * 64 + r)) * 3072 + DMODEL + (size_t)h * HDIM + cc;
  const f32x4* kp = (const f32x4*)(qkv + gk);
  const f32x4* vp = (const f32x4*)(qkv + gk + DMODEL);
  f32x4* kd = (f32x4*)(&Kl[r][cc]);
  f32x4* vd = (f32x4*)(&Vl[r][cc]);
  kd[0]=kp[0]; kd[1]=kp[1]; kd[2]=kp[2]; kd[3]=kp[3];
  vd[0]=vp[0]; vd[1]=vp[1]; vd[2]=vp[2]; vd[3]=vp[3];
}

__global__ __launch_bounds__(256, 1) void attn_f4(
    const float* __restrict__ qkv,
    float* __restrict__ ctx)
{
  __shared__ float Kl[64][68];
  __shared__ float Vl[64][68];
  int bh = blockIdx.y;
  int b = bh >> 4, h = bh & 15;
  int p = blockIdx.x;                  // 0..7
  int tid = threadIdx.x;
  int ql = tid >> 2, d0 = (tid & 3) * 16;
  int qtA = p, qtB = 15 - p;           // 128-row q-tiles
  int rA0 = qtA * 128 + ql, rA1 = rA0 + 64;
  int rB0 = qtB * 128 + ql, rB1 = rB0 + 64;
  const int bS = b * SEQ;
  const size_t hoff = (size_t)h * HDIM + d0;

  f32x4 qA0[4], qA1[4], qB0[4], qB1[4];
  {
    const f32x4* pa0 = (const f32x4*)(qkv + (size_t)(bS + rA0) * 3072 + hoff);
    const f32x4* pa1 = (const f32x4*)(qkv + (size_t)(bS + rA1) * 3072 + hoff);
    const f32x4* pb0 = (const f32x4*)(qkv + (size_t)(bS + rB0) * 3072 + hoff);
    const f32x4* pb1 = (const f32x4*)(qkv + (size_t)(bS + rB1) * 3072 + hoff);
    #pragma unroll
    for (int i = 0; i < 4; ++i) {
      qA0[i] = pa0[i]; qA1[i] = pa1[i]; qB0[i] = pb0[i]; qB1[i] = pb1[i];
    }
  }
  const f32x4 z = {0.f, 0.f, 0.f, 0.f};
  f32x4 oA0[4], oA1[4], oB0[4], oB1[4];
  #pragma unroll
  for (int i = 0; i < 4; ++i) { oA0[i]=z; oA1[i]=z; oB0[i]=z; oB1[i]=z; }
  float mA0=-1e30f, lA0=0.f, mA1=-1e30f, lA1=0.f;
  float mB0=-1e30f, lB0=0.f, mB1=-1e30f, lB1=0.f;

  int ktAend = 2 * qtA + 1, ktBend = 2 * qtB + 1;

  // phase 1: all 4 rows active (B rows always unmasked here)
  for (int kt = 0; kt <= ktAend; ++kt) {
    __syncthreads();
    attn_load_tile(qkv, Kl, Vl, bS, h, kt, tid);
    __syncthreads();
    int kt64 = kt * 64;
    int relA0 = rA0 - kt64, relA1 = rA1 - kt64;
    for (int jb = 0; jb < 64; jb += 8) {
      float s0[8], s1[8], s2[8], s3[8];
      #pragma unroll
      for (int j = 0; j < 8; ++j) {
        int jj = jb + j;
        const f32x4* kr = (const f32x4*)(&Kl[jj][d0]);
        f32x4 k0v = kr[0], k1v = kr[1], k2v = kr[2], k3v = kr[3];
        float d0v = DOT4(qA0);
        float d1v = DOT4(qA1);
        float d2v = DOT4(qB0);
        float d3v = DOT4(qB1);
        d0v += __shfl_xor(d0v, 1); d0v += __shfl_xor(d0v, 2);
        d1v += __shfl_xor(d1v, 1); d1v += __shfl_xor(d1v, 2);
        d2v += __shfl_xor(d2v, 1); d2v += __shfl_xor(d2v, 2);
        d3v += __shfl_xor(d3v, 1); d3v += __shfl_xor(d3v, 2);
        s0[j] = (jj <= relA0) ? d0v * 0.125f : -1e30f;
        s1[j] = (jj <= relA1) ? d1v * 0.125f : -1e30f;
        s2[j] = d2v * 0.125f;
        s3[j] = d3v * 0.125f;
      }
      float c0 = CMAX8(s0), c1 = CMAX8(s1), c2 = CMAX8(s2), c3 = CMAX8(s3);
      UPD(c0, mA0, lA0, oA0);
      UPD(c1, mA1, lA1, oA1);
      UPD(c2, mB0, lB0, oB0);
      UPD(c3, mB1, lB1, oB1);
      #pragma unroll
      for (int j = 0; j < 8; ++j) {
        const f32x4* vr = (const f32x4*)(&Vl[jb + j][d0]);
        f32x4 v0v = vr[0], v1v = vr[1], v2v = vr[2], v3v = vr[3];
        PVROW(s0, mA0, lA0, oA0);
        PVROW(s1, mA1, lA1, oA1);
        PVROW(s2, mB0, lB0, oB0);
        PVROW(s3, mB1, lB1, oB1);
      }
    }
  }

  // phase 2: only B rows
  for (int kt = ktAend + 1; kt <= ktBend; ++kt) {
    __syncthreads();
    attn_load_tile(qkv, Kl, Vl, bS, h, kt, tid);
    __syncthreads();
    int kt64 = kt * 64;
    int relB0 = rB0 - kt64, relB1 = rB1 - kt64;
    int jend = relB1 < 63 ? relB1 : 63;
    for (int jb = 0; jb <= jend; jb += 8) {
      float s2[8], s3[8];
      #pragma unroll
      for (int j = 0; j < 8; ++j) {
        int jj = jb + j;
        const f32x4* kr = (const f32x4*)(&Kl[jj][d0]);
        f32x4 k0v = kr[0], k1v = kr[1], k2v = kr[2], k3v = kr[3];
        float d2v = DOT4(qB0);
        float d3v = DOT4(qB1);
        d2v += __shfl_xor(d2v, 1); d2v += __shfl_xor(d2v, 2);
        d3v += __shfl_xor(d3v, 1); d3v += __shfl_xor(d3v, 2);
        s2[j] = (jj <= relB0) ? d2v * 0.125f : -1e30f;
        s3[j] = (jj <= relB1) ? d3v * 0.125f : -1e30f;
      }
      float c2 = CMAX8(s2), c3 = CMAX8(s3);
      UPD(c2, mB0, lB0, oB0);
      UPD(c3, mB1, lB1, oB1);
      #pragma unroll
      for (int j = 0; j < 8; ++j) {
        const f32x4* vr = (const f32x4*)(&Vl[jb + j][d0]);
        f32x4 v0v = vr[0], v1v = vr[1], v2v = vr[2], v3v = vr[3];
        PVROW(s2, mB0, lB0, oB0);
        PVROW(s3, mB1, lB1, oB1);
      }
    }
  }

  {
    float inv = 1.0f / lA0;
    float* orow = ctx + (size_t)(bS + rA0) * DMODEL + hoff;
    #pragma unroll
    for (int i = 0; i < 4; ++i) ((f32x4*)orow)[i] = oA0[i] * inv;
  }
  {
    float inv = 1.0f / lA1;
    float* orow = ctx + (size_t)(bS + rA1) * DMODEL + hoff;
    #pragma unroll
    for (int i = 0; i < 4; ++i) ((f32x4*)orow)[i] = oA1[i] * inv;
  }
  {
    float inv = 1.0f / lB0;
    float* orow = ctx + (size_t)(bS + rB0) * DMODEL + hoff;
    #pragma unroll
    for (int i = 0; i < 4; ++i) ((f32x4*)orow)[i] = oB0[i] * inv;
  }
  {
    float inv = 1.0f / lB1;
    float* orow = ctx + (size_t)(bS + rB1) * DMODEL + hoff;
    #pragma unroll
    for (int i = 0; i < 4; ++i) ((f32x4*)orow)[i] = oB1[i] * inv;
  }
}

// ---------------------------------------------------------------------------
// Router (fp32)
// ---------------------------------------------------------------------------
__global__ __launch_bounds__(256) void router_kernel(
    const float* __restrict__ x1,
    const float* __restrict__ gam,
    const float* __restrict__ bet,
    const float* __restrict__ wrt,
    int* __restrict__ ctrl,
    int2* __restrict__ t_e,
    float2* __restrict__ t_g)
{
  int w = threadIdx.x >> 6, l = threadIdx.x & 63;
  int t = blockIdx.x * 4 + w;
  const f32x4* row = (const f32x4*)(x1 + (size_t)t * DMODEL);
  f32x4 v[4];
  float s = 0.f, sq = 0.f;
  #pragma unroll
  for (int i = 0; i < 4; ++i) {
    v[i] = row[l + i * 64];
    #pragma unroll
    for (int j = 0; j < 4; ++j) { s += v[i][j]; sq += v[i][j] * v[i][j]; }
  }
  #pragma unroll
  for (int off = 1; off < 64; off <<= 1) {
    s  += __shfl_xor(s, off);
    sq += __shfl_xor(sq, off);
  }
  float mu  = s * (1.0f / DMODEL);
  float var = sq * (1.0f / DMODEL) - mu * mu;
  float rs  = rsqrtf(var + 1e-5f);

  float acc[NE] = {0.f, 0.f, 0.f, 0.f, 0.f, 0.f, 0.f, 0.f};
  #pragma unroll
  for (int i = 0; i < 4; ++i) {
    int base = (l + i * 64) * 4;
    #pragma unroll
    for (int j = 0; j < 4; ++j) {
      int idx = base + j;
      float xn = (v[i][j] - mu) * rs * gam[idx] + bet[idx];
      const f32x4* wr0 = (const f32x4*)(wrt + idx * NE);
      f32x4 w0 = wr0[0], w1v = wr0[1];
      acc[0] += xn * w0[0]; acc[1] += xn * w0[1];
      acc[2] += xn * w0[2]; acc[3] += xn * w0[3];
      acc[4] += xn * w1v[0]; acc[5] += xn * w1v[1];
      acc[6] += xn * w1v[2]; acc[7] += xn * w1v[3];
    }
  }
  #pragma unroll
  for (int e = 0; e < NE; ++e) {
    #pragma unroll
    for (int off = 1; off < 64; off <<= 1) acc[e] += __shfl_xor(acc[e], off);
  }
  if (l == 0) {
    int e0 = 0; float m0v = acc[0];
    #pragma unroll
    for (int e = 1; e < NE; ++e) if (acc[e] > m0v) { m0v = acc[e]; e0 = e; }
    int e1 = -1; float m1v = -1e30f;
    #pragma unroll
    for (int e = 0; e < NE; ++e) if (e != e0 && acc[e] > m1v) { m1v = acc[e]; e1 = e; }
    float r = __expf(m1v - m0v);
    float g0 = 1.0f / (1.0f + r);
    float g1 = r * g0;
    t_e[t] = make_int2(e0, e1);
    t_g[t] = make_float2(g0, g1);
    atomicAdd(&ctrl[C_CNT + e0], 1);
    atomicAdd(&ctrl[C_CNT + e1], 1);
  }
}

// ---------------------------------------------------------------------------
__global__ void scan_kernel(int* __restrict__ ctrl)
{
  if (threadIdx.x == 0 && blockIdx.x == 0) {
    int b = 0, m = 0;
    for (int e = 0; e < NE; ++e) {
      ctrl[C_BASE + e] = b;
      int pc = (ctrl[C_CNT + e] + 127) & ~127;
      int nt = pc >> 7;
      for (int i = 0; i < nt; ++i) {
        ctrl[C_MTE + m] = e;
        ctrl[C_MTS + m] = b + (i << 7);
        ++m;
      }
      b += pc;
    }
    ctrl[C_NMT] = m;
  }
}

// ---------------------------------------------------------------------------
__global__ __launch_bounds__(256) void gather_kernel(
    int* __restrict__ ctrl,
    const int2* __restrict__ t_e,
    const float2* __restrict__ t_g,
    int* __restrict__ slot_token,
    float* __restrict__ slot_gate)
{
  int t = blockIdx.x * 256 + threadIdx.x;
  int2 e = t_e[t];
  float2 g = t_g[t];
  int p0 = atomicAdd(&ctrl[C_FILL + e.x], 1);
  int s0 = ctrl[C_BASE + e.x] + p0;
  slot_token[s0] = t; slot_gate[s0] = g.x;
  int p1 = atomicAdd(&ctrl[C_FILL + e.y], 1);
  int s1 = ctrl[C_BASE + e.y] + p1;
  slot_token[s1] = t; slot_gate[s1] = g.y;
}

// ---------------------------------------------------------------------------
// Transpose + fp32->bf16 convert: in [E][K][N] fp32 -> out [E][N][K] bf16.
// Grid (N/64, K/64, E), block 256.
// ---------------------------------------------------------------------------
__global__ __launch_bounds__(256) void transpose_conv(
    const float* __restrict__ in, unsigned short* __restrict__ outb,
    int K, int N)
{
  __shared__ float T[64][68];
  int e = blockIdx.z;
  int n0 = blockIdx.x * 64, k0 = blockIdx.y * 64;
  const float* src = in + (size_t)e * K * N;
  unsigned short* dst = outb + (size_t)e * K * N;
  int tid = threadIdx.x;
  int r = tid >> 4, c4 = (tid & 15) * 4;
  #pragma unroll
  for (int i = 0; i < 4; ++i) {
    f32x4 v = *(const f32x4*)(src + (size_t)(k0 + r + i * 16) * N + n0 + c4);
    *(f32x4*)(&T[r + i * 16][c4]) = v;
  }
  __syncthreads();
  #pragma unroll
  for (int i = 0; i < 4; ++i) {
    int rr = r + i * 16;               // n offset
    ushort4 o;
    o.x = f2bf(T[c4 + 0][rr]);
    o.y = f2bf(T[c4 + 1][rr]);
    o.z = f2bf(T[c4 + 2][rr]);
    o.w = f2bf(T[c4 + 3][rr]);
    *(ushort4*)(dst + (size_t)(n0 + rr) * K + k0 + c4) = o;
  }
}

// ---------------------------------------------------------------------------
// Sparse MoE w1: Hs[slot] = gelu(h2[token(slot)] @ w1[e] + b1[e]).
// BT=true: Bt is pre-transposed bf16 [N][K]; else Bm fp32 [K][N].
// ---------------------------------------------------------------------------
template<bool BT>
__global__ __launch_bounds__(256) void moe_w1(
    const unsigned short* __restrict__ h2,
    const float* __restrict__ w1,
    const unsigned short* __restrict__ w1t,
    const float* __restrict__ b1,
    const int* __restrict__ ctrl,
    const int* __restrict__ slot_token,
    unsigned short* __restrict__ Hs)
{
  int mt = blockIdx.y;
  if (mt >= ctrl[C_NMT]) return;
  int e = ctrl[C_MTE + mt];
  int slot0 = ctrl[C_MTS + mt];
  const int N = DFF, K = DMODEL;
  const float* Bm = w1 + (size_t)e * K * N;
  const unsigned short* Bt = w1t + (size_t)e * K * N;
  const float* bias = b1 + (size_t)e * DFF;

  __shared__ unsigned short Al[128][40];
  __shared__ unsigned short Bl[128][40];
  __shared__ int tokrow[128];
  int tid = threadIdx.x;
  if (tid < 128) {
    int tk = slot_token[slot0 + tid];
    tokrow[tid] = tk < 0 ? 0 : tk;
  }
  int l = tid & 63, w = tid >> 6;
  int wr = w >> 1, wc = w & 1;
  int n0 = blockIdx.x * 128;

  const f32x4 z = {0.f, 0.f, 0.f, 0.f};
  f32x4 acc[4][4];
  #pragma unroll
  for (int i = 0; i < 4; ++i)
    #pragma unroll
    for (int j = 0; j < 4; ++j) acc[i][j] = z;

  for (int k0 = 0; k0 < K; k0 += 32) {
    __syncthreads();
    for (int c = tid; c < 512; c += 256) {
      int row = c >> 2, kc = (c & 3) << 3;
      uint4v v = *(const uint4v*)(h2 + (size_t)tokrow[row] * DMODEL + k0 + kc);
      *(uint4v*)(&Al[row][kc]) = v;
    }
    if constexpr (BT) {
      for (int c = tid; c < 512; c += 256) {
        int row = c >> 2, kc = (c & 3) << 3;
        uint4v v = *(const uint4v*)(Bt + (size_t)(n0 + row) * K + k0 + kc);
        *(uint4v*)(&Bl[row][kc]) = v;
      }
    } else {
      for (int c = tid; c < 1024; c += 256) {
        int k = c >> 5, nc = (c & 31) << 2;
        f32x4 v = *(const f32x4*)(Bm + (size_t)(k0 + k) * N + n0 + nc);
        Bl[nc + 0][k] = f2bf(v[0]);
        Bl[nc + 1][k] = f2bf(v[1]);
        Bl[nc + 2][k] = f2bf(v[2]);
        Bl[nc + 3][k] = f2bf(v[3]);
      }
    }
    __syncthreads();

    short8 af[4], bfr[4];
    #pragma unroll
    for (int m = 0; m < 4; ++m)
      af[m] = *(const short8*)(&Al[wr * 64 + m * 16 + (l & 15)][(l >> 4) << 3]);
    #pragma unroll
    for (int n = 0; n < 4; ++n)
      bfr[n] = *(const short8*)(&Bl[wc * 64 + n * 16 + (l & 15)][(l >> 4) << 3]);
    #pragma unroll
    for (int m = 0; m < 4; ++m)
      #pragma unroll
      for (int n = 0; n < 4; ++n)
        acc[m][n] = __builtin_amdgcn_mfma_f32_16x16x32_bf16(af[m], bfr[n], acc[m][n], 0, 0, 0);
  }

  int rbase = wr * 64 + ((l >> 4) << 2);
  int cbase = n0 + wc * 64 + (l & 15);
  #pragma unroll
  for (int n = 0; n < 4; ++n) {
    int col = cbase + n * 16;
    float bv = bias[col];
    #pragma unroll
    for (int m = 0; m < 4; ++m) {
      #pragma unroll
      for (int r = 0; r < 4; ++r) {
        int srow = slot0 + rbase + m * 16 + r;
        float v = acc[m][n][r] + bv;
        v = 0.5f * v * (1.0f + erff(v * 0.70710678118654752f));
        Hs[(size_t)srow * DFF + col] = f2bf(v);
      }
    }
  }
}

// ---------------------------------------------------------------------------
// Sparse MoE w2: ffn[token(slot)] += gate(slot)*(Hs[slot] @ w2[e] + b2[e])
// ---------------------------------------------------------------------------
template<bool BT>
__global__ __launch_bounds__(256) void moe_w2(
    const unsigned short* __restrict__ Hs,
    const float* __restrict__ w2,
    const unsigned short* __restrict__ w2t,
    const float* __restrict__ b2,
    const int* __restrict__ ctrl,
    const int* __restrict__ slot_token,
    const float* __restrict__ slot_gate,
    float* __restrict__ ffn)
{
  int mt = blockIdx.y;
  if (mt >= ctrl[C_NMT]) return;
  int e = ctrl[C_MTE + mt];
  int slot0 = ctrl[C_MTS + mt];
  const int N = DMODEL, K = DFF;
  const float* Bm = w2 + (size_t)e * K * N;
  const unsigned short* Bt = w2t + (size_t)e * K * N;
  const float* bias = b2 + (size_t)e * DMODEL;

  __shared__ unsigned short Al[128][40];
  __shared__ unsigned short Bl[128][40];
  int tid = threadIdx.x;
  int l = tid & 63, w = tid >> 6;
  int wr = w >> 1, wc = w & 1;
  int n0 = blockIdx.x * 128;

  const f32x4 z = {0.f, 0.f, 0.f, 0.f};
  f32x4 acc[4][4];
  #pragma unroll
  for (int i = 0; i < 4; ++i)
    #pragma unroll
    for (int j = 0; j < 4; ++j) acc[i][j] = z;

  for (int k0 = 0; k0 < K; k0 += 32) {
    __syncthreads();
    for (int c = tid; c < 512; c += 256) {
      int row = c >> 2, kc = (c & 3) << 3;
      uint4v v = *(const uint4v*)(Hs + (size_t)(slot0 + row) * DFF + k0 + kc);
      *(uint4v*)(&Al[row][kc]) = v;
    }
    if constexpr (BT) {
      for (int c = tid; c < 512; c += 256) {
        int row = c >> 2, kc = (c & 3) << 3;
        uint4v v = *(const uint4v*)(Bt + (size_t)(n0 + row) * K + k0 + kc);
        *(uint4v*)(&Bl[row][kc]) = v;
      }
    } else {
      for (int c = tid; c < 1024; c += 256) {
        int k = c >> 5, nc = (c & 31) << 2;
        f32x4 v = *(const f32x4*)(Bm + (size_t)(k0 + k) * N + n0 + nc);
        Bl[nc + 0][k] = f2bf(v[0]);
        Bl[nc + 1][k] = f2bf(v[1]);
        Bl[nc + 2][k] = f2bf(v[2]);
        Bl[nc + 3][k] = f2bf(v[3]);
      }
    }
    __syncthreads();

    short8 af[4], bfr[4];
    #pragma unroll
    for (int m = 0; m < 4; ++m)
      af[m] = *(const short8*)(&Al[wr * 64 + m * 16 + (l & 15)][(l >> 4) << 3]);
    #pragma unroll
    for (int n = 0; n < 4; ++n)
      bfr[n] = *(const short8*)(&Bl[wc * 64 + n * 16 + (l & 15)][(l >> 4) << 3]);
    #pragma unroll
    for (int m = 0; m < 4; ++m)
      #pragma unroll
      for (int n = 0; n < 4; ++n)
        acc[m][n] = __builtin_amdgcn_mfma_f32_16x16x32_bf16(af[m], bfr[n], acc[m][n], 0, 0, 0);
  }

  int rbase = wr * 64 + ((l >> 4) << 2);
  int cbase = n0 + wc * 64 + (l & 15);
  #pragma unroll
  for (int n = 0; n < 4; ++n) {
    int col = cbase + n * 16;
    float bv = bias[col];
    #pragma unroll
    for (int m = 0; m < 4; ++m) {
      #pragma unroll
      for (int r = 0; r < 4; ++r) {
        int srow = slot0 + rbase + m * 16 + r;
        int tok = slot_token[srow];
        if (tok >= 0) {
          float v = acc[m][n][r] + bv;
          atomicAdd(&ffn[(size_t)tok * DMODEL + col], slot_gate[srow] * v);
        }
      }
    }
  }
}

// ---------------------------------------------------------------------------
__global__ __launch_bounds__(256) void final_add(
    const float* __restrict__ x1,
    const float* __restrict__ ffn,
    float* __restrict__ out)
{
  int i = blockIdx.x * 256 + threadIdx.x;
  f32x4 xr = ((const f32x4*)x1)[i];
  f32x4 fr = ((const f32x4*)ffn)[i];
  f32x4 o;
  o[0] = xr[0] + fr[0];
  o[1] = xr[1] + fr[1];
  o[2] = xr[2] + fr[2];
  o[3] = xr[3] + fr[3];
  ((f32x4*)out)[i] = o;
}

// ---------------------------------------------------------------------------
extern "C" void kernel_launch(void* const* d_in, const int* in_sizes, int n_in,
                              void* d_out, int out_size, void* d_ws, size_t ws_size,
                              hipStream_t stream) {
  (void)in_sizes; (void)n_in; (void)out_size;
  const float* x     = (const float*)d_in[0];
  const float* ln1_g = (const float*)d_in[1];
  const float* ln1_b = (const float*)d_in[2];
  const float* ln2_g = (const float*)d_in[3];
  const float* ln2_b = (const float*)d_in[4];
  const float* wqkv  = (const float*)d_in[5];
  const float* bqkv  = (const float*)d_in[6];
  const float* wo    = (const float*)d_in[7];
  const float* bo    = (const float*)d_in[8];
  const float* wrt   = (const float*)d_in[9];
  const float* w1    = (const float*)d_in[10];
  const float* b1    = (const float*)d_in[11];
  const float* w2    = (const float*)d_in[12];
  const float* b2    = (const float*)d_in[13];
  float* out = (float*)d_out;

  char* ws = (char*)d_ws;
  size_t off = 0;
  auto alloc = [&](size_t bytes) -> void* {
    void* p = ws + off;
    off += (bytes + 255) & ~(size_t)255;
    return p;
  };
  float*          x1    = (float*)alloc((size_t)TTOK * DMODEL * 4);
  unsigned short* h2    = (unsigned short*)alloc((size_t)TTOK * DMODEL * 2);
  int*            ctrl  = (int*)alloc(1024);
  int2*           t_e   = (int2*)alloc((size_t)TTOK * 8);
  float2*         t_g   = (float2*)alloc((size_t)TTOK * 8);
  int*            slot_token = (int*)alloc((size_t)SLOT_MAX * 4);
  float*          slot_gate  = (float*)alloc((size_t)SLOT_MAX * 4);
  float*          P1    = (float*)alloc((size_t)TTOK * DMODEL * 4);
  char*           P2    = (char*)alloc((size_t)SLOT_MAX * DFF * 2);
  // optional pre-transposed bf16 weights
  unsigned short* w1t   = (unsigned short*)alloc((size_t)NE * DMODEL * DFF * 2);
  unsigned short* w2t   = (unsigned short*)alloc((size_t)NE * DFF * DMODEL * 2);
  bool PRE = (off <= ws_size);

  float*          h    = P1;
  float*          qkv  = (float*)P2;
  float*          ctx  = P1;
  float*          ffn  = P1;
  unsigned short* Hs   = (unsigned short*)P2;

  // 0) zero control counters, mark all slots invalid
  hipMemsetAsync(ctrl, 0, 16 * 4, stream);
  hipMemsetAsync(slot_token, 0xFF, (size_t)SLOT_MAX * 4, stream);

  // 0b) pre-transpose + convert MoE weights (bf16 [N][K]) if ws permits
  if (PRE) {
    transpose_conv<<<dim3(DFF / 64, DMODEL / 64, NE), 256, 0, stream>>>(
        w1, w1t, DMODEL, DFF);
    transpose_conv<<<dim3(DMODEL / 64, DFF / 64, NE), 256, 0, stream>>>(
        w2, w2t, DFF, DMODEL);
  }

  // 1) h = LN1(x)
  ln_kernel<false><<<TTOK, 256, 0, stream>>>(x, ln1_g, ln1_b, h, nullptr);
  // 2) qkv = h @ wqkv + bqkv   (fp32 — precision-critical path)
  sgemm128<0><<<dim3(3 * DMODEL / 128, TTOK / 128), 256, 0, stream>>>(
      h, wqkv, bqkv, nullptr, qkv, TTOK, 3 * DMODEL, DMODEL);
  // 3) ctx = causal attention (fp32, 4 q-rows/thread, fold-balanced)
  attn_f4<<<dim3(SEQ / 256, NB * NH), 256, 0, stream>>>(qkv, ctx);
  // 4) x1 = x + ctx @ wo + bo
  sgemm128<1><<<dim3(DMODEL / 128, TTOK / 128), 256, 0, stream>>>(
      ctx, wo, bo, x, x1, TTOK, DMODEL, DMODEL);
  // 5) h2 = LN2(x1)
  ln_kernel<true><<<TTOK, 256, 0, stream>>>(x1, ln2_g, ln2_b, nullptr, h2);
  // 6) router -> scan -> gather
  router_kernel<<<TTOK / 4, 256, 0, stream>>>(x1, ln2_g, ln2_b, wrt, ctrl, t_e, t_g);
  scan_kernel<<<1, 64, 0, stream>>>(ctrl);
  gather_kernel<<<TTOK / 256, 256, 0, stream>>>(ctrl, t_e, t_g, slot_token, slot_gate);
  // 7) sparse MoE
  hipMemsetAsync(ffn, 0, (size_t)TTOK * DMODEL * 4, stream);
  if (PRE) {
    moe_w1<true><<<dim3(DFF / 128, MT_MAX), 256, 0, stream>>>(
        h2, w1, w1t, b1, ctrl, slot_token, Hs);
    moe_w2<true><<<dim3(DMODEL / 128, MT_MAX), 256, 0, stream>>>(
        Hs, w2, w2t, b2, ctrl, slot_token, slot_gate, ffn);
  } else {
    moe_w1<false><<<dim3(DFF / 128, MT_MAX), 256, 0, stream>>>(
        h2, w1, w1t, b1, ctrl, slot_token, Hs);
    moe_w2<false><<<dim3(DMODEL / 128, MT_MAX), 256, 0, stream>>>(
        Hs, w2, w2t, b2, ctrl, slot_token, slot_gate, ffn);
  }
  // 8) out = x1 + ffn
  final_add<<<(TTOK * DMODEL / 4) / 256, 256, 0, stream>>>(x1, ffn, out);
}